// Round 2
// baseline (2839.741 us; speedup 1.0000x reference)
//
#include <hip/hip_runtime.h>
#include <hip/hip_bf16.h>

#define NN 100000
#define NE 3200000
#define D 64
#define ZS 256   // z row stride (DIM * (L+1))
#define BN_EPS 1e-5f

// ---- embedding gather: z[:, 0:64] = embed_deg[node_deg] ----
__global__ __launch_bounds__(256) void embed_kernel(const int* __restrict__ deg,
    const float* __restrict__ emb, float* __restrict__ z) {
  int idx = blockIdx.x * 256 + threadIdx.x;   // over NN*64
  int i = idx >> 6, d = idx & 63;
  if (i < NN) z[(long)i * ZS + d] = emb[(long)deg[i] * D + d];
}

// ---- edge scatter: agg[dst] += z[src, col:col+64] ----
__global__ __launch_bounds__(256) void scatter_kernel(const int* __restrict__ ei,
    const float* __restrict__ z, int col, float* __restrict__ agg) {
  long t = (long)blockIdx.x * 256 + threadIdx.x;
  long e = t >> 6;
  int d = (int)(t & 63);
  if (e < NE) {
    int s = ei[e];
    int dd = ei[NE + e];
    atomicAdd(&agg[(long)dd * D + d], z[(long)s * ZS + col + d]);
  }
}

// ---- generic 64-wide GEMM: Y[i,d] = act(bias[d] + sum_k Xeff[i,k] * W[k,d])
//      Xeff = alpha*X + AGG when AGG != null (K must be 64 then)
__global__ __launch_bounds__(256) void gemm_kernel(
    const float* __restrict__ X, int xstride, int K,
    const float* __restrict__ AGG, const float* __restrict__ epsv, int l,
    const float* __restrict__ W, const float* __restrict__ bias,
    float* __restrict__ Y, int ystride, int leaky)
{
  __shared__ float Ws[64][64];
  __shared__ float Xs[4][64];
  int tid = threadIdx.x;
  int d = tid & 63, q = tid >> 6;
  int i = blockIdx.x * 4 + q;
  float alpha = (AGG != nullptr) ? (1.0f + epsv[l]) : 1.0f;
  float acc = bias[d];
  for (int kc = 0; kc < K; kc += 64) {
    __syncthreads();
    #pragma unroll
    for (int r = 0; r < 64; r += 4)
      Ws[r + q][d] = W[(long)(kc + r + q) * D + d];
    float xv = X[(long)i * xstride + kc + d];
    if (AGG) xv = alpha * xv + AGG[(long)i * D + d];
    Xs[q][d] = xv;
    __syncthreads();
    #pragma unroll
    for (int k = 0; k < 64; k++)
      acc += Xs[q][k] * Ws[k][d];
  }
  if (leaky) acc = (acc >= 0.0f) ? acc : 0.01f * acc;
  Y[(long)i * ystride + d] = acc;
}

// ---- BN stats: stats[0:64] = sum, stats[64:128] = sumsq (per column) ----
__global__ __launch_bounds__(256) void bn_stats_kernel(const float* __restrict__ Y,
    int ystride, float* __restrict__ stats) {
  int tid = threadIdx.x;
  int d = tid & 63, q = tid >> 6;
  float s = 0.0f, ss = 0.0f;
  for (int i = blockIdx.x * 4 + q; i < NN; i += gridDim.x * 4) {
    float v = Y[(long)i * ystride + d];
    s += v;
    ss += v * v;
  }
  __shared__ float Ss[4][64], SSs[4][64];
  Ss[q][d] = s; SSs[q][d] = ss;
  __syncthreads();
  if (q == 0) {
    s  = Ss[0][d] + Ss[1][d] + Ss[2][d] + Ss[3][d];
    ss = SSs[0][d] + SSs[1][d] + SSs[2][d] + SSs[3][d];
    atomicAdd(&stats[d], s);
    atomicAdd(&stats[64 + d], ss);
  }
}

// ---- BN apply + leaky ----
__global__ __launch_bounds__(256) void bn_apply_kernel(const float* __restrict__ Y,
    int ystride, const float* __restrict__ stats,
    const float* __restrict__ g, const float* __restrict__ b,
    float* __restrict__ Out, int ostride) {
  int idx = blockIdx.x * 256 + threadIdx.x;
  int i = idx >> 6, d = idx & 63;
  if (i >= NN) return;
  float invn = 1.0f / (float)NN;
  float mu = stats[d] * invn;
  float var = fmaxf(stats[64 + d] * invn - mu * mu, 0.0f);
  float sc = g[d] * rsqrtf(var + BN_EPS);
  float v = sc * (Y[(long)i * ystride + d] - mu) + b[d];
  v = (v >= 0.0f) ? v : 0.01f * v;
  Out[(long)i * ostride + d] = v;
}

// ---- fc2: out[i] = sigmoid(dot(H[i,:], W) + b), wave per row ----
__global__ __launch_bounds__(256) void fc2_kernel(const float* __restrict__ H,
    const float* __restrict__ W, const float* __restrict__ b,
    float* __restrict__ out) {
  int tid = threadIdx.x;
  int k = tid & 63, q = tid >> 6;
  int i = blockIdx.x * 4 + q;
  float v = (i < NN) ? H[(long)i * D + k] * W[k] : 0.0f;
  #pragma unroll
  for (int off = 32; off > 0; off >>= 1)
    v += __shfl_down(v, off);
  if (k == 0 && i < NN) {
    float x = v + b[0];
    out[i] = 1.0f / (1.0f + __expf(-x));
  }
}

extern "C" void kernel_launch(void* const* d_in, const int* in_sizes, int n_in,
                              void* d_out, int out_size, void* d_ws, size_t ws_size,
                              hipStream_t stream) {
  const int*   node_deg   = (const int*)d_in[0];
  const int*   edge_index = (const int*)d_in[1];
  const float* embed      = (const float*)d_in[2];
  const float* eps        = (const float*)d_in[3];
  const float* W1         = (const float*)d_in[4];
  const float* b1         = (const float*)d_in[5];
  const float* W2         = (const float*)d_in[6];
  const float* b2         = (const float*)d_in[7];
  const float* bn_g       = (const float*)d_in[8];
  const float* bn_b       = (const float*)d_in[9];
  const float* fc_W1      = (const float*)d_in[10];
  const float* fc_b1      = (const float*)d_in[11];
  const float* fc_bn_g    = (const float*)d_in[12];
  const float* fc_bn_b    = (const float*)d_in[13];
  const float* fc_W2      = (const float*)d_in[14];
  const float* fc_b2      = (const float*)d_in[15];

  float* zbuf  = (float*)d_ws;            // [NN, 256]
  float* agg   = zbuf + (long)NN * ZS;    // [NN, 64]
  float* tmp   = agg + (long)NN * D;      // [NN, 64]
  float* stats = tmp + (long)NN * D;      // [128]

  const int rowBlocks = NN / 4;           // 25000
  const int scatBlocks = (int)(((long)NE * 64 + 255) / 256);  // 800000

  embed_kernel<<<rowBlocks, 256, 0, stream>>>(node_deg, embed, zbuf);

  for (int l = 0; l < 3; ++l) {
    hipMemsetAsync(agg, 0, (size_t)NN * D * sizeof(float), stream);
    scatter_kernel<<<scatBlocks, 256, 0, stream>>>(edge_index, zbuf, l * D, agg);
    // h1 = leaky((1+eps)x + agg) @ W1 + b1)
    gemm_kernel<<<rowBlocks, 256, 0, stream>>>(zbuf + l * D, ZS, 64,
        agg, eps, l, W1 + (long)l * D * D, b1 + (long)l * D, tmp, D, 1);
    // y = h1 @ W2 + b2  (pre-BN) into z slice l+1
    gemm_kernel<<<rowBlocks, 256, 0, stream>>>(tmp, D, 64,
        nullptr, nullptr, 0, W2 + (long)l * D * D, b2 + (long)l * D,
        zbuf + (l + 1) * D, ZS, 0);
    hipMemsetAsync(stats, 0, 128 * sizeof(float), stream);
    bn_stats_kernel<<<256, 256, 0, stream>>>(zbuf + (l + 1) * D, ZS, stats);
    bn_apply_kernel<<<rowBlocks, 256, 0, stream>>>(zbuf + (l + 1) * D, ZS, stats,
        bn_g + (long)l * D, bn_b + (long)l * D, zbuf + (l + 1) * D, ZS);
  }

  // fc1: [N,256] @ [256,64] + b  -> agg (pre-BN)
  gemm_kernel<<<rowBlocks, 256, 0, stream>>>(zbuf, ZS, 256,
      nullptr, nullptr, 0, fc_W1, fc_b1, agg, D, 0);
  hipMemsetAsync(stats, 0, 128 * sizeof(float), stream);
  bn_stats_kernel<<<256, 256, 0, stream>>>(agg, D, stats);
  bn_apply_kernel<<<rowBlocks, 256, 0, stream>>>(agg, D, stats,
      fc_bn_g, fc_bn_b, tmp, D);
  // fc2 + sigmoid -> f32 out
  fc2_kernel<<<rowBlocks, 256, 0, stream>>>(tmp, fc_W2, fc_b2, (float*)d_out);
}

// Round 3
// 1932.010 us; speedup vs baseline: 1.4698x; 1.4698x over previous
//
#include <hip/hip_runtime.h>
#include <hip/hip_bf16.h>

#define NN 100000
#define NE 3200000
#define D 64
#define BN_EPS 1e-5f
#define SCAN_B 391   // ceil(NN/256)

// ---- embedding gather: cur = embed_deg[node_deg]  [N,64] ----
__global__ __launch_bounds__(256) void embed_kernel(const int* __restrict__ deg,
    const float* __restrict__ emb, float* __restrict__ cur) {
  int idx = blockIdx.x * 256 + threadIdx.x;
  int i = idx >> 6, d = idx & 63;
  if (i < NN) cur[(long)i * D + d] = emb[(long)deg[i] * D + d];
}

// ---- CSR build: histogram of dst ----
__global__ __launch_bounds__(256) void hist_kernel(const int* __restrict__ ei,
    int* __restrict__ cnt) {
  int e = blockIdx.x * 256 + threadIdx.x;
  if (e < NE) atomicAdd(&cnt[ei[NE + e]], 1);
}

// ---- scan pass 1: per-block sums of cnt ----
__global__ __launch_bounds__(256) void scan1_kernel(const int* __restrict__ cnt,
    int* __restrict__ bsum) {
  __shared__ int sh[256];
  int t = threadIdx.x;
  int i = blockIdx.x * 256 + t;
  int v = (i < NN) ? cnt[i] : 0;
  sh[t] = v;
  __syncthreads();
  for (int o = 128; o > 0; o >>= 1) {
    if (t < o) sh[t] += sh[t + o];
    __syncthreads();
  }
  if (t == 0) bsum[blockIdx.x] = sh[0];
}

// ---- scan pass 2: exclusive scan of block sums (single block, 512 thr) ----
__global__ __launch_bounds__(512) void scan2_kernel(int* __restrict__ bsum) {
  __shared__ int sh[512];
  int t = threadIdx.x;
  int v = (t < SCAN_B) ? bsum[t] : 0;
  sh[t] = v;
  __syncthreads();
  for (int o = 1; o < 512; o <<= 1) {
    int x = (t >= o) ? sh[t - o] : 0;
    __syncthreads();
    sh[t] += x;
    __syncthreads();
  }
  if (t < SCAN_B) bsum[t] = sh[t] - v;   // exclusive
}

// ---- scan pass 3: csr_off[i] = bsum[blk] + excl_within; cursor=csr_off ----
__global__ __launch_bounds__(256) void scan3_kernel(int* __restrict__ cnt,
    const int* __restrict__ bsum, int* __restrict__ csr_off) {
  __shared__ int sh[256];
  int t = threadIdx.x;
  int i = blockIdx.x * 256 + t;
  int v = (i < NN) ? cnt[i] : 0;
  sh[t] = v;
  __syncthreads();
  for (int o = 1; o < 256; o <<= 1) {
    int x = (t >= o) ? sh[t - o] : 0;
    __syncthreads();
    sh[t] += x;
    __syncthreads();
  }
  if (i < NN) {
    int off = bsum[blockIdx.x] + sh[t] - v;  // exclusive prefix
    csr_off[i] = off;
    cnt[i] = off;                            // cnt becomes cursor for fill
  }
  if (blockIdx.x == 0 && t == 0) csr_off[NN] = NE;
}

// ---- CSR fill: csr_src[pos] = src, bucketed by dst ----
__global__ __launch_bounds__(256) void fill_kernel(const int* __restrict__ ei,
    int* __restrict__ cursor, int* __restrict__ csr_src) {
  int e = blockIdx.x * 256 + threadIdx.x;
  if (e < NE) {
    int s = ei[e];
    int dd = ei[NE + e];
    int p = atomicAdd(&cursor[dd], 1);
    csr_src[p] = s;
  }
}

// ---- aggregation: agg[i,:] = sum over in-edges of x[src,:]  (wave/node) ----
__global__ __launch_bounds__(256) void agg_kernel(const int* __restrict__ off,
    const int* __restrict__ srcs, const float* __restrict__ x,
    float* __restrict__ agg) {
  int t = threadIdx.x;
  int d = t & 63, q = t >> 6;
  int i = blockIdx.x * 4 + q;
  int e0 = off[i], e1 = off[i + 1];
  float s = 0.0f;
  for (int e = e0; e < e1; e++) {
    int j = srcs[e];
    s += x[(long)j * D + d];
  }
  agg[(long)i * D + d] = s;
}

// ---- 64-wide GEMM: Y[i,d] = act(init + sum_k Xeff[i,k] * W[k,d])
//      Xeff = alpha*X + AGG when AGG != null; init = Y (accum) or bias or 0
__global__ __launch_bounds__(256) void gemm_kernel(
    const float* __restrict__ X, int K,
    const float* __restrict__ AGG, const float* __restrict__ epsv, int l,
    const float* __restrict__ W, const float* __restrict__ bias,
    float* Y, int leaky, int accum)
{
  __shared__ float Ws[64][64];
  __shared__ float Xs[4][64];
  int tid = threadIdx.x;
  int d = tid & 63, q = tid >> 6;
  int i = blockIdx.x * 4 + q;
  float alpha = (AGG != nullptr) ? (1.0f + epsv[l]) : 1.0f;
  float acc = accum ? Y[(long)i * D + d] : (bias ? bias[d] : 0.0f);
  for (int kc = 0; kc < K; kc += 64) {
    __syncthreads();
    #pragma unroll
    for (int r = 0; r < 64; r += 4)
      Ws[r + q][d] = W[(long)(kc + r + q) * D + d];
    float xv = X[(long)i * D + kc + d];
    if (AGG) xv = alpha * xv + AGG[(long)i * D + d];
    Xs[q][d] = xv;
    __syncthreads();
    #pragma unroll
    for (int k = 0; k < 64; k++)
      acc += Xs[q][k] * Ws[k][d];
  }
  if (leaky) acc = (acc >= 0.0f) ? acc : 0.01f * acc;
  Y[(long)i * D + d] = acc;
}

// ---- BN stats: stats[0:64]=sum, stats[64:128]=sumsq ----
__global__ __launch_bounds__(256) void bn_stats_kernel(const float* __restrict__ Y,
    float* __restrict__ stats) {
  int tid = threadIdx.x;
  int d = tid & 63, q = tid >> 6;
  float s = 0.0f, ss = 0.0f;
  for (int i = blockIdx.x * 4 + q; i < NN; i += gridDim.x * 4) {
    float v = Y[(long)i * D + d];
    s += v;
    ss += v * v;
  }
  __shared__ float Ss[4][64], SSs[4][64];
  Ss[q][d] = s; SSs[q][d] = ss;
  __syncthreads();
  if (q == 0) {
    s  = Ss[0][d] + Ss[1][d] + Ss[2][d] + Ss[3][d];
    ss = SSs[0][d] + SSs[1][d] + SSs[2][d] + SSs[3][d];
    atomicAdd(&stats[d], s);
    atomicAdd(&stats[64 + d], ss);
  }
}

// ---- BN apply + leaky ----
__global__ __launch_bounds__(256) void bn_apply_kernel(const float* __restrict__ Y,
    const float* __restrict__ stats,
    const float* __restrict__ g, const float* __restrict__ b,
    float* __restrict__ Out) {
  int idx = blockIdx.x * 256 + threadIdx.x;
  int i = idx >> 6, d = idx & 63;
  if (i >= NN) return;
  float invn = 1.0f / (float)NN;
  float mu = stats[d] * invn;
  float var = fmaxf(stats[64 + d] * invn - mu * mu, 0.0f);
  float sc = g[d] * rsqrtf(var + BN_EPS);
  float v = sc * (Y[(long)i * D + d] - mu) + b[d];
  v = (v >= 0.0f) ? v : 0.01f * v;
  Out[(long)i * D + d] = v;
}

// ---- fc2: out[i] = sigmoid(dot(H[i,:], W) + b) ----
__global__ __launch_bounds__(256) void fc2_kernel(const float* __restrict__ H,
    const float* __restrict__ W, const float* __restrict__ b,
    float* __restrict__ out) {
  int tid = threadIdx.x;
  int k = tid & 63, q = tid >> 6;
  int i = blockIdx.x * 4 + q;
  float v = (i < NN) ? H[(long)i * D + k] * W[k] : 0.0f;
  #pragma unroll
  for (int off = 32; off > 0; off >>= 1)
    v += __shfl_down(v, off);
  if (k == 0 && i < NN) {
    float x = v + b[0];
    out[i] = 1.0f / (1.0f + __expf(-x));
  }
}

extern "C" void kernel_launch(void* const* d_in, const int* in_sizes, int n_in,
                              void* d_out, int out_size, void* d_ws, size_t ws_size,
                              hipStream_t stream) {
  const int*   node_deg   = (const int*)d_in[0];
  const int*   edge_index = (const int*)d_in[1];
  const float* embed      = (const float*)d_in[2];
  const float* eps        = (const float*)d_in[3];
  const float* W1         = (const float*)d_in[4];
  const float* b1         = (const float*)d_in[5];
  const float* W2         = (const float*)d_in[6];
  const float* b2         = (const float*)d_in[7];
  const float* bn_g       = (const float*)d_in[8];
  const float* bn_b       = (const float*)d_in[9];
  const float* fc_W1      = (const float*)d_in[10];
  const float* fc_b1      = (const float*)d_in[11];
  const float* fc_bn_g    = (const float*)d_in[12];
  const float* fc_bn_b    = (const float*)d_in[13];
  const float* fc_W2      = (const float*)d_in[14];
  const float* fc_b2      = (const float*)d_in[15];

  // workspace layout (floats then ints): 5*[N,64] f32 + stats + CSR arrays
  float* cur    = (float*)d_ws;                 // [N,64]
  float* nxt    = cur + (long)NN * D;           // [N,64]
  float* fc1acc = nxt + (long)NN * D;           // [N,64]
  float* agg    = fc1acc + (long)NN * D;        // [N,64]
  float* tmp    = agg + (long)NN * D;           // [N,64]
  float* stats  = tmp + (long)NN * D;           // [128]
  int*   cnt    = (int*)(stats + 128);          // [NN]   (cnt -> cursor)
  int*   csroff = cnt + NN;                     // [NN+1]
  int*   bsum   = csroff + NN + 1;              // [512]
  int*   csrsrc = bsum + 512;                   // [NE]

  const int rowBlocks  = NN / 4;                 // 25000
  const int edgeBlocks = (NE + 255) / 256;       // 12500

  // ---- build CSR (by dst) once per call ----
  hipMemsetAsync(cnt, 0, (size_t)NN * sizeof(int), stream);
  hist_kernel<<<edgeBlocks, 256, 0, stream>>>(edge_index, cnt);
  scan1_kernel<<<SCAN_B, 256, 0, stream>>>(cnt, bsum);
  scan2_kernel<<<1, 512, 0, stream>>>(bsum);
  scan3_kernel<<<SCAN_B, 256, 0, stream>>>(cnt, bsum, csroff);
  fill_kernel<<<edgeBlocks, 256, 0, stream>>>(edge_index, cnt, csrsrc);

  // ---- embedding + fc1 contribution of slice 0 ----
  embed_kernel<<<rowBlocks, 256, 0, stream>>>(node_deg, embed, cur);
  gemm_kernel<<<rowBlocks, 256, 0, stream>>>(cur, 64, nullptr, nullptr, 0,
      fc_W1, fc_b1, fc1acc, 0, 0);

  for (int l = 0; l < 3; ++l) {
    agg_kernel<<<rowBlocks, 256, 0, stream>>>(csroff, csrsrc, cur, agg);
    // tmp = leaky(((1+eps)x + agg) @ W1 + b1)
    gemm_kernel<<<rowBlocks, 256, 0, stream>>>(cur, 64, agg, eps, l,
        W1 + (long)l * D * D, b1 + (long)l * D, tmp, 1, 0);
    // nxt = tmp @ W2 + b2  (pre-BN)
    gemm_kernel<<<rowBlocks, 256, 0, stream>>>(tmp, 64, nullptr, nullptr, 0,
        W2 + (long)l * D * D, b2 + (long)l * D, nxt, 0, 0);
    hipMemsetAsync(stats, 0, 128 * sizeof(float), stream);
    bn_stats_kernel<<<256, 256, 0, stream>>>(nxt, stats);
    bn_apply_kernel<<<rowBlocks, 256, 0, stream>>>(nxt, stats,
        bn_g + (long)l * D, bn_b + (long)l * D, nxt);
    // fc1acc += nxt @ fc_W1[(l+1)*64 : (l+2)*64, :]
    gemm_kernel<<<rowBlocks, 256, 0, stream>>>(nxt, 64, nullptr, nullptr, 0,
        fc_W1 + (long)(l + 1) * D * D, nullptr, fc1acc, 0, 1);
    float* t2 = cur; cur = nxt; nxt = t2;  // swap
  }

  // ---- fc1 BN + leaky -> tmp; fc2 + sigmoid -> out ----
  hipMemsetAsync(stats, 0, 128 * sizeof(float), stream);
  bn_stats_kernel<<<256, 256, 0, stream>>>(fc1acc, stats);
  bn_apply_kernel<<<rowBlocks, 256, 0, stream>>>(fc1acc, stats,
      fc_bn_g, fc_bn_b, tmp);
  fc2_kernel<<<rowBlocks, 256, 0, stream>>>(tmp, fc_W2, fc_b2, (float*)d_out);
}

// Round 4
// 1223.364 us; speedup vs baseline: 2.3213x; 1.5793x over previous
//
#include <hip/hip_runtime.h>
#include <hip/hip_bf16.h>

#define NN 100000
#define NE 3200000
#define D 64
#define BN_EPS 1e-5f
#define SCAN_B 391   // ceil(NN/256)

// ---- embedding gather: cur = embed_deg[node_deg]  [N,64] ----
__global__ __launch_bounds__(256) void embed_kernel(const int* __restrict__ deg,
    const float* __restrict__ emb, float* __restrict__ cur) {
  int idx = blockIdx.x * 256 + threadIdx.x;
  int i = idx >> 6, d = idx & 63;
  if (i < NN) cur[(long)i * D + d] = emb[(long)deg[i] * D + d];
}

// ---- CSR build: histogram of dst ----
__global__ __launch_bounds__(256) void hist_kernel(const int* __restrict__ ei,
    int* __restrict__ cnt) {
  int e = blockIdx.x * 256 + threadIdx.x;
  if (e < NE) atomicAdd(&cnt[ei[NE + e]], 1);
}

// ---- scan pass 1: per-block sums of cnt ----
__global__ __launch_bounds__(256) void scan1_kernel(const int* __restrict__ cnt,
    int* __restrict__ bsum) {
  __shared__ int sh[256];
  int t = threadIdx.x;
  int i = blockIdx.x * 256 + t;
  int v = (i < NN) ? cnt[i] : 0;
  sh[t] = v;
  __syncthreads();
  for (int o = 128; o > 0; o >>= 1) {
    if (t < o) sh[t] += sh[t + o];
    __syncthreads();
  }
  if (t == 0) bsum[blockIdx.x] = sh[0];
}

// ---- scan pass 2: exclusive scan of block sums (single block, 512 thr) ----
__global__ __launch_bounds__(512) void scan2_kernel(int* __restrict__ bsum) {
  __shared__ int sh[512];
  int t = threadIdx.x;
  int v = (t < SCAN_B) ? bsum[t] : 0;
  sh[t] = v;
  __syncthreads();
  for (int o = 1; o < 512; o <<= 1) {
    int x = (t >= o) ? sh[t - o] : 0;
    __syncthreads();
    sh[t] += x;
    __syncthreads();
  }
  if (t < SCAN_B) bsum[t] = sh[t] - v;   // exclusive
}

// ---- scan pass 3: csr_off[i] = bsum[blk] + excl_within; cursor=csr_off ----
__global__ __launch_bounds__(256) void scan3_kernel(int* __restrict__ cnt,
    const int* __restrict__ bsum, int* __restrict__ csr_off) {
  __shared__ int sh[256];
  int t = threadIdx.x;
  int i = blockIdx.x * 256 + t;
  int v = (i < NN) ? cnt[i] : 0;
  sh[t] = v;
  __syncthreads();
  for (int o = 1; o < 256; o <<= 1) {
    int x = (t >= o) ? sh[t - o] : 0;
    __syncthreads();
    sh[t] += x;
    __syncthreads();
  }
  if (i < NN) {
    int off = bsum[blockIdx.x] + sh[t] - v;  // exclusive prefix
    csr_off[i] = off;
    cnt[i] = off;                            // cnt becomes cursor for fill
  }
  if (blockIdx.x == 0 && t == 0) csr_off[NN] = NE;
}

// ---- CSR fill: csr_src[pos] = src, bucketed by dst ----
__global__ __launch_bounds__(256) void fill_kernel(const int* __restrict__ ei,
    int* __restrict__ cursor, int* __restrict__ csr_src) {
  int e = blockIdx.x * 256 + threadIdx.x;
  if (e < NE) {
    int s = ei[e];
    int dd = ei[NE + e];
    int p = atomicAdd(&cursor[dd], 1);
    csr_src[p] = s;
  }
}

// ---- aggregation: agg[i,:] = sum over in-edges of x[src,:]  (wave/node) ----
// 8-way unrolled: 8 independent gathers in flight per wave
__global__ __launch_bounds__(256) void agg_kernel(const int* __restrict__ off,
    const int* __restrict__ srcs, const float* __restrict__ x,
    float* __restrict__ agg) {
  int t = threadIdx.x;
  int d = t & 63, q = t >> 6;
  int i = blockIdx.x * 4 + q;
  int e0 = off[i], e1 = off[i + 1];
  float s = 0.0f;
  int e = e0;
  for (; e + 8 <= e1; e += 8) {
    int j0 = srcs[e + 0], j1 = srcs[e + 1], j2 = srcs[e + 2], j3 = srcs[e + 3];
    int j4 = srcs[e + 4], j5 = srcs[e + 5], j6 = srcs[e + 6], j7 = srcs[e + 7];
    float v0 = x[(long)j0 * D + d], v1 = x[(long)j1 * D + d];
    float v2 = x[(long)j2 * D + d], v3 = x[(long)j3 * D + d];
    float v4 = x[(long)j4 * D + d], v5 = x[(long)j5 * D + d];
    float v6 = x[(long)j6 * D + d], v7 = x[(long)j7 * D + d];
    s += ((v0 + v1) + (v2 + v3)) + ((v4 + v5) + (v6 + v7));
  }
  for (; e < e1; e++) s += x[(long)srcs[e] * D + d];
  agg[(long)i * D + d] = s;
}

// ---- 64x64-tiled GEMM (K=64): Y[i,d] = act(init + sum_k Xeff[i,k] * W[k,d])
//      Xeff = alpha*X + AGG when AGG != null; init = Y (accum) or bias
//      256 threads, 4x4 register tile per thread, X transposed in LDS.
__global__ __launch_bounds__(256) void gemm64_kernel(
    const float* __restrict__ X,
    const float* __restrict__ AGG, const float* __restrict__ epsv, int l,
    const float* __restrict__ W, const float* __restrict__ bias,
    float* Y, int leaky, int accum)
{
  __shared__ float Ws[64][64];     // Ws[k][d]
  __shared__ float XsT[64][64];    // XsT[k][row]
  int t = threadIdx.x;
  int i0 = blockIdx.x * 64;
  float alpha = (AGG != nullptr) ? (1.0f + epsv[l]) : 1.0f;

  // stage W (coalesced float4)
  {
    int wr = t >> 4;              // 0..15
    int wc = (t & 15) * 4;        // 0..60
    #pragma unroll
    for (int j = 0; j < 4; j++) {
      float4 w4 = *(const float4*)&W[(long)(wr + 16 * j) * D + wc];
      *(float4*)&Ws[wr + 16 * j][wc] = w4;
    }
  }
  // stage X (+eps/agg fusion), transposed
  {
    int row = t & 63;
    int gi = i0 + row;
    int gis = (gi < NN) ? gi : NN - 1;   // clamp: loads valid, stores guarded
    int kb = (t >> 6) * 16;
    #pragma unroll
    for (int j = 0; j < 4; j++) {
      int k = kb + 4 * j;
      float4 xv = *(const float4*)&X[(long)gis * D + k];
      if (AGG) {
        float4 a4 = *(const float4*)&AGG[(long)gis * D + k];
        xv.x = alpha * xv.x + a4.x;
        xv.y = alpha * xv.y + a4.y;
        xv.z = alpha * xv.z + a4.z;
        xv.w = alpha * xv.w + a4.w;
      }
      XsT[k + 0][row] = xv.x;
      XsT[k + 1][row] = xv.y;
      XsT[k + 2][row] = xv.z;
      XsT[k + 3][row] = xv.w;
    }
  }

  int c0 = (t & 15) * 4;     // col base
  int r0 = (t >> 4) * 4;     // row base
  float4 acc[4];
  if (accum) {
    #pragma unroll
    for (int r = 0; r < 4; r++) {
      int gi = i0 + r0 + r;
      int gis = (gi < NN) ? gi : NN - 1;
      acc[r] = *(const float4*)&Y[(long)gis * D + c0];
    }
  } else {
    float4 b4 = *(const float4*)&bias[c0];
    #pragma unroll
    for (int r = 0; r < 4; r++) acc[r] = b4;
  }
  __syncthreads();

  #pragma unroll 8
  for (int k = 0; k < 64; k++) {
    float4 w4 = *(const float4*)&Ws[k][c0];
    float4 x4 = *(const float4*)&XsT[k][r0];
    acc[0].x += x4.x * w4.x; acc[0].y += x4.x * w4.y;
    acc[0].z += x4.x * w4.z; acc[0].w += x4.x * w4.w;
    acc[1].x += x4.y * w4.x; acc[1].y += x4.y * w4.y;
    acc[1].z += x4.y * w4.z; acc[1].w += x4.y * w4.w;
    acc[2].x += x4.z * w4.x; acc[2].y += x4.z * w4.y;
    acc[2].z += x4.z * w4.z; acc[2].w += x4.z * w4.w;
    acc[3].x += x4.w * w4.x; acc[3].y += x4.w * w4.y;
    acc[3].z += x4.w * w4.z; acc[3].w += x4.w * w4.w;
  }

  #pragma unroll
  for (int r = 0; r < 4; r++) {
    int gi = i0 + r0 + r;
    if (gi < NN) {
      float4 v = acc[r];
      if (leaky) {
        v.x = (v.x >= 0.0f) ? v.x : 0.01f * v.x;
        v.y = (v.y >= 0.0f) ? v.y : 0.01f * v.y;
        v.z = (v.z >= 0.0f) ? v.z : 0.01f * v.z;
        v.w = (v.w >= 0.0f) ? v.w : 0.01f * v.w;
      }
      *(float4*)&Y[(long)gi * D + c0] = v;
    }
  }
}

// ---- BN stats: stats[0:64]=sum, stats[64:128]=sumsq ----
__global__ __launch_bounds__(256) void bn_stats_kernel(const float* __restrict__ Y,
    float* __restrict__ stats) {
  int tid = threadIdx.x;
  int d = tid & 63, q = tid >> 6;
  float s = 0.0f, ss = 0.0f;
  for (int i = blockIdx.x * 4 + q; i < NN; i += gridDim.x * 4) {
    float v = Y[(long)i * D + d];
    s += v;
    ss += v * v;
  }
  __shared__ float Ss[4][64], SSs[4][64];
  Ss[q][d] = s; SSs[q][d] = ss;
  __syncthreads();
  if (q == 0) {
    s  = Ss[0][d] + Ss[1][d] + Ss[2][d] + Ss[3][d];
    ss = SSs[0][d] + SSs[1][d] + SSs[2][d] + SSs[3][d];
    atomicAdd(&stats[d], s);
    atomicAdd(&stats[64 + d], ss);
  }
}

// ---- BN apply + leaky ----
__global__ __launch_bounds__(256) void bn_apply_kernel(const float* __restrict__ Y,
    const float* __restrict__ stats,
    const float* __restrict__ g, const float* __restrict__ b,
    float* __restrict__ Out) {
  int idx = blockIdx.x * 256 + threadIdx.x;
  int i = idx >> 6, d = idx & 63;
  if (i >= NN) return;
  float invn = 1.0f / (float)NN;
  float mu = stats[d] * invn;
  float var = fmaxf(stats[64 + d] * invn - mu * mu, 0.0f);
  float sc = g[d] * rsqrtf(var + BN_EPS);
  float v = sc * (Y[(long)i * D + d] - mu) + b[d];
  v = (v >= 0.0f) ? v : 0.01f * v;
  Out[(long)i * D + d] = v;
}

// ---- fc2: out[i] = sigmoid(dot(H[i,:], W) + b) ----
__global__ __launch_bounds__(256) void fc2_kernel(const float* __restrict__ H,
    const float* __restrict__ W, const float* __restrict__ b,
    float* __restrict__ out) {
  int tid = threadIdx.x;
  int k = tid & 63, q = tid >> 6;
  int i = blockIdx.x * 4 + q;
  float v = (i < NN) ? H[(long)i * D + k] * W[k] : 0.0f;
  #pragma unroll
  for (int off = 32; off > 0; off >>= 1)
    v += __shfl_down(v, off);
  if (k == 0 && i < NN) {
    float x = v + b[0];
    out[i] = 1.0f / (1.0f + __expf(-x));
  }
}

extern "C" void kernel_launch(void* const* d_in, const int* in_sizes, int n_in,
                              void* d_out, int out_size, void* d_ws, size_t ws_size,
                              hipStream_t stream) {
  const int*   node_deg   = (const int*)d_in[0];
  const int*   edge_index = (const int*)d_in[1];
  const float* embed      = (const float*)d_in[2];
  const float* eps        = (const float*)d_in[3];
  const float* W1         = (const float*)d_in[4];
  const float* b1         = (const float*)d_in[5];
  const float* W2         = (const float*)d_in[6];
  const float* b2         = (const float*)d_in[7];
  const float* bn_g       = (const float*)d_in[8];
  const float* bn_b       = (const float*)d_in[9];
  const float* fc_W1      = (const float*)d_in[10];
  const float* fc_b1      = (const float*)d_in[11];
  const float* fc_bn_g    = (const float*)d_in[12];
  const float* fc_bn_b    = (const float*)d_in[13];
  const float* fc_W2      = (const float*)d_in[14];
  const float* fc_b2      = (const float*)d_in[15];

  // workspace layout (floats then ints): 5*[N,64] f32 + stats + CSR arrays
  float* cur    = (float*)d_ws;                 // [N,64]
  float* nxt    = cur + (long)NN * D;           // [N,64]
  float* fc1acc = nxt + (long)NN * D;           // [N,64]
  float* agg    = fc1acc + (long)NN * D;        // [N,64]
  float* tmp    = agg + (long)NN * D;           // [N,64]
  float* stats  = tmp + (long)NN * D;           // [128]
  int*   cnt    = (int*)(stats + 128);          // [NN]   (cnt -> cursor)
  int*   csroff = cnt + NN;                     // [NN+1]
  int*   bsum   = csroff + NN + 1;              // [512]
  int*   csrsrc = bsum + 512;                   // [NE]

  const int rowBlocks  = NN / 4;                 // 25000
  const int gemmBlocks = (NN + 63) / 64;         // 1563
  const int edgeBlocks = (NE + 255) / 256;       // 12500

  // ---- build CSR (by dst) once per call ----
  hipMemsetAsync(cnt, 0, (size_t)NN * sizeof(int), stream);
  hist_kernel<<<edgeBlocks, 256, 0, stream>>>(edge_index, cnt);
  scan1_kernel<<<SCAN_B, 256, 0, stream>>>(cnt, bsum);
  scan2_kernel<<<1, 512, 0, stream>>>(bsum);
  scan3_kernel<<<SCAN_B, 256, 0, stream>>>(cnt, bsum, csroff);
  fill_kernel<<<edgeBlocks, 256, 0, stream>>>(edge_index, cnt, csrsrc);

  // ---- embedding + fc1 contribution of slice 0 ----
  embed_kernel<<<rowBlocks, 256, 0, stream>>>(node_deg, embed, cur);
  gemm64_kernel<<<gemmBlocks, 256, 0, stream>>>(cur, nullptr, nullptr, 0,
      fc_W1, fc_b1, fc1acc, 0, 0);

  for (int l = 0; l < 3; ++l) {
    agg_kernel<<<rowBlocks, 256, 0, stream>>>(csroff, csrsrc, cur, agg);
    // tmp = leaky(((1+eps)x + agg) @ W1 + b1)
    gemm64_kernel<<<gemmBlocks, 256, 0, stream>>>(cur, agg, eps, l,
        W1 + (long)l * D * D, b1 + (long)l * D, tmp, 1, 0);
    // nxt = tmp @ W2 + b2  (pre-BN)
    gemm64_kernel<<<gemmBlocks, 256, 0, stream>>>(tmp, nullptr, nullptr, 0,
        W2 + (long)l * D * D, b2 + (long)l * D, nxt, 0, 0);
    hipMemsetAsync(stats, 0, 128 * sizeof(float), stream);
    bn_stats_kernel<<<256, 256, 0, stream>>>(nxt, stats);
    bn_apply_kernel<<<rowBlocks, 256, 0, stream>>>(nxt, stats,
        bn_g + (long)l * D, bn_b + (long)l * D, nxt);
    // fc1acc += nxt @ fc_W1[(l+1)*64 : (l+2)*64, :]
    gemm64_kernel<<<gemmBlocks, 256, 0, stream>>>(nxt, nullptr, nullptr, 0,
        fc_W1 + (long)(l + 1) * D * D, nullptr, fc1acc, 0, 1);
    float* t2 = cur; cur = nxt; nxt = t2;  // swap
  }

  // ---- fc1 BN + leaky -> tmp; fc2 + sigmoid -> out ----
  hipMemsetAsync(stats, 0, 128 * sizeof(float), stream);
  bn_stats_kernel<<<256, 256, 0, stream>>>(fc1acc, stats);
  bn_apply_kernel<<<rowBlocks, 256, 0, stream>>>(fc1acc, stats,
      fc_bn_g, fc_bn_b, tmp);
  fc2_kernel<<<rowBlocks, 256, 0, stream>>>(tmp, fc_W2, fc_b2, (float*)d_out);
}

// Round 5
// 1052.335 us; speedup vs baseline: 2.6985x; 1.1625x over previous
//
#include <hip/hip_runtime.h>
#include <hip/hip_bf16.h>

#define NN 100000
#define NE 3200000
#define D 64
#define BN_EPS 1e-5f
#define SCAN_B 391   // ceil(NN/256)

#define NP 512       // producer blocks
#define CHUNK 6250   // edges per producer (512*6250 = 3.2M exactly)
#define NB 391       // dst buckets of 256 nodes (391*256 = 100096 >= NN)

// ---- embedding gather: cur = embed_deg[node_deg]  [N,64] ----
__global__ __launch_bounds__(256) void embed_kernel(const int* __restrict__ deg,
    const float* __restrict__ emb, float* __restrict__ cur) {
  int idx = blockIdx.x * 256 + threadIdx.x;
  int i = idx >> 6, d = idx & 63;
  if (i < NN) cur[(long)i * D + d] = emb[(long)deg[i] * D + d];
}

// ---- producer: bucket edges into private per-block regions (packed records)
//      rec = src | (dstLocal << 17); also fused global per-node histogram.
__global__ __launch_bounds__(256) void bucket_kernel(const int* __restrict__ ei,
    int* __restrict__ rec, int* __restrict__ S, int* __restrict__ cnt) {
  __shared__ int cntL[392];     // bucket counts (padded)
  __shared__ int curL[392];     // bucket cursors
  __shared__ int scanbuf[256];
  int t = threadIdx.x;
  int p = blockIdx.x;
  int e0 = p * CHUNK;
  cntL[t] = 0;
  if (t < 136) cntL[256 + t] = 0;
  __syncthreads();
  // pass 1: bucket histogram (LDS) + global per-node histogram (fused)
  for (int e = t; e < CHUNK; e += 256) {
    int dd = ei[NE + e0 + e];
    atomicAdd(&cntL[(unsigned)dd >> 8], 1);
    atomicAdd(&cnt[dd], 1);
  }
  __syncthreads();
  // exclusive scan over 392 counters: 196 thread-pairs + block scan
  int a0 = 0, a1 = 0;
  if (t < 196) { a0 = cntL[2 * t]; a1 = cntL[2 * t + 1]; }
  int s = a0 + a1;
  scanbuf[t] = s;
  __syncthreads();
  for (int off = 1; off < 256; off <<= 1) {
    int x = (t >= off) ? scanbuf[t - off] : 0;
    __syncthreads();
    scanbuf[t] += x;
    __syncthreads();
  }
  int ex = scanbuf[t] - s;   // exclusive over pair sums
  if (t < 196) {
    curL[2 * t]     = ex;
    curL[2 * t + 1] = ex + a0;
    S[p * 392 + 2 * t]     = e0 + ex;
    S[p * 392 + 2 * t + 1] = e0 + ex + a0;   // t=195 -> boundary S[p][391]=e0+6250
  }
  __syncthreads();
  // pass 2: scatter packed records into MY private region (write-amp ~1)
  for (int e = t; e < CHUNK; e += 256) {
    int ss = ei[e0 + e];
    int dd = ei[NE + e0 + e];
    int b = (unsigned)dd >> 8;
    int pos = atomicAdd(&curL[b], 1);
    rec[e0 + pos] = ss | ((dd & 255) << 17);
  }
}

// ---- scan pass 1: per-block sums of cnt ----
__global__ __launch_bounds__(256) void scan1_kernel(const int* __restrict__ cnt,
    int* __restrict__ bsum) {
  __shared__ int sh[256];
  int t = threadIdx.x;
  int i = blockIdx.x * 256 + t;
  int v = (i < NN) ? cnt[i] : 0;
  sh[t] = v;
  __syncthreads();
  for (int o = 128; o > 0; o >>= 1) {
    if (t < o) sh[t] += sh[t + o];
    __syncthreads();
  }
  if (t == 0) bsum[blockIdx.x] = sh[0];
}

// ---- scan pass 2: exclusive scan of block sums ----
__global__ __launch_bounds__(512) void scan2_kernel(int* __restrict__ bsum) {
  __shared__ int sh[512];
  int t = threadIdx.x;
  int v = (t < SCAN_B) ? bsum[t] : 0;
  sh[t] = v;
  __syncthreads();
  for (int o = 1; o < 512; o <<= 1) {
    int x = (t >= o) ? sh[t - o] : 0;
    __syncthreads();
    sh[t] += x;
    __syncthreads();
  }
  if (t < SCAN_B) bsum[t] = sh[t] - v;   // exclusive
}

// ---- scan pass 3: csr_off[i] = bsum[blk] + excl_within ----
__global__ __launch_bounds__(256) void scan3_kernel(const int* __restrict__ cnt,
    const int* __restrict__ bsum, int* __restrict__ csr_off) {
  __shared__ int sh[256];
  int t = threadIdx.x;
  int i = blockIdx.x * 256 + t;
  int v = (i < NN) ? cnt[i] : 0;
  sh[t] = v;
  __syncthreads();
  for (int o = 1; o < 256; o <<= 1) {
    int x = (t >= o) ? sh[t - o] : 0;
    __syncthreads();
    sh[t] += x;
    __syncthreads();
  }
  if (i < NN) csr_off[i] = bsum[blockIdx.x] + sh[t] - v;
  if (blockIdx.x == 0 && t == 0) csr_off[NN] = NE;
}

// ---- sorter: one block per bucket; scatter records into csr_src
//      (bucket's csr range is block-owned -> no cross-XCD line sharing) ----
__global__ __launch_bounds__(256) void sort_kernel(const int* __restrict__ rec,
    const int* __restrict__ S, const int* __restrict__ csroff,
    int* __restrict__ csrsrc) {
  __shared__ int curL[256];
  int t = threadIdx.x;
  int B = blockIdx.x;
  int node = B * 256 + t;
  curL[t] = (node < NN) ? csroff[node] : 0;
  __syncthreads();
  int lane = t & 63, wq = t >> 6;
  for (int p = wq; p < NP; p += 4) {
    int s0 = S[p * 392 + B], s1 = S[p * 392 + B + 1];
    for (int e = s0 + lane; e < s1; e += 64) {
      int r = rec[e];
      int src = r & 0x1FFFF;
      int dl = (unsigned)r >> 17;
      int pos = atomicAdd(&curL[dl], 1);
      csrsrc[pos] = src;
    }
  }
}

// ---- aggregation: agg[i,:] = sum over in-edges of x[src,:]  (wave/node) ----
__global__ __launch_bounds__(256) void agg_kernel(const int* __restrict__ off,
    const int* __restrict__ srcs, const float* __restrict__ x,
    float* __restrict__ agg) {
  int t = threadIdx.x;
  int d = t & 63, q = t >> 6;
  int i = blockIdx.x * 4 + q;
  int e0 = off[i], e1 = off[i + 1];
  float s = 0.0f;
  int e = e0;
  for (; e + 8 <= e1; e += 8) {
    int j0 = srcs[e + 0], j1 = srcs[e + 1], j2 = srcs[e + 2], j3 = srcs[e + 3];
    int j4 = srcs[e + 4], j5 = srcs[e + 5], j6 = srcs[e + 6], j7 = srcs[e + 7];
    float v0 = x[(long)j0 * D + d], v1 = x[(long)j1 * D + d];
    float v2 = x[(long)j2 * D + d], v3 = x[(long)j3 * D + d];
    float v4 = x[(long)j4 * D + d], v5 = x[(long)j5 * D + d];
    float v6 = x[(long)j6 * D + d], v7 = x[(long)j7 * D + d];
    s += ((v0 + v1) + (v2 + v3)) + ((v4 + v5) + (v6 + v7));
  }
  for (; e < e1; e++) s += x[(long)srcs[e] * D + d];
  agg[(long)i * D + d] = s;
}

// ---- 64x64-tiled GEMM (K=64), 4x4 register tile per thread ----
__global__ __launch_bounds__(256) void gemm64_kernel(
    const float* __restrict__ X,
    const float* __restrict__ AGG, const float* __restrict__ epsv, int l,
    const float* __restrict__ W, const float* __restrict__ bias,
    float* Y, int leaky, int accum)
{
  __shared__ float Ws[64][64];     // Ws[k][d]
  __shared__ float XsT[64][64];    // XsT[k][row]
  int t = threadIdx.x;
  int i0 = blockIdx.x * 64;
  float alpha = (AGG != nullptr) ? (1.0f + epsv[l]) : 1.0f;

  {
    int wr = t >> 4;
    int wc = (t & 15) * 4;
    #pragma unroll
    for (int j = 0; j < 4; j++) {
      float4 w4 = *(const float4*)&W[(long)(wr + 16 * j) * D + wc];
      *(float4*)&Ws[wr + 16 * j][wc] = w4;
    }
  }
  {
    int row = t & 63;
    int gi = i0 + row;
    int gis = (gi < NN) ? gi : NN - 1;
    int kb = (t >> 6) * 16;
    #pragma unroll
    for (int j = 0; j < 4; j++) {
      int k = kb + 4 * j;
      float4 xv = *(const float4*)&X[(long)gis * D + k];
      if (AGG) {
        float4 a4 = *(const float4*)&AGG[(long)gis * D + k];
        xv.x = alpha * xv.x + a4.x;
        xv.y = alpha * xv.y + a4.y;
        xv.z = alpha * xv.z + a4.z;
        xv.w = alpha * xv.w + a4.w;
      }
      XsT[k + 0][row] = xv.x;
      XsT[k + 1][row] = xv.y;
      XsT[k + 2][row] = xv.z;
      XsT[k + 3][row] = xv.w;
    }
  }

  int c0 = (t & 15) * 4;
  int r0 = (t >> 4) * 4;
  float4 acc[4];
  if (accum) {
    #pragma unroll
    for (int r = 0; r < 4; r++) {
      int gi = i0 + r0 + r;
      int gis = (gi < NN) ? gi : NN - 1;
      acc[r] = *(const float4*)&Y[(long)gis * D + c0];
    }
  } else {
    float4 b4 = *(const float4*)&bias[c0];
    #pragma unroll
    for (int r = 0; r < 4; r++) acc[r] = b4;
  }
  __syncthreads();

  #pragma unroll 8
  for (int k = 0; k < 64; k++) {
    float4 w4 = *(const float4*)&Ws[k][c0];
    float4 x4 = *(const float4*)&XsT[k][r0];
    acc[0].x += x4.x * w4.x; acc[0].y += x4.x * w4.y;
    acc[0].z += x4.x * w4.z; acc[0].w += x4.x * w4.w;
    acc[1].x += x4.y * w4.x; acc[1].y += x4.y * w4.y;
    acc[1].z += x4.y * w4.z; acc[1].w += x4.y * w4.w;
    acc[2].x += x4.z * w4.x; acc[2].y += x4.z * w4.y;
    acc[2].z += x4.z * w4.z; acc[2].w += x4.z * w4.w;
    acc[3].x += x4.w * w4.x; acc[3].y += x4.w * w4.y;
    acc[3].z += x4.w * w4.z; acc[3].w += x4.w * w4.w;
  }

  #pragma unroll
  for (int r = 0; r < 4; r++) {
    int gi = i0 + r0 + r;
    if (gi < NN) {
      float4 v = acc[r];
      if (leaky) {
        v.x = (v.x >= 0.0f) ? v.x : 0.01f * v.x;
        v.y = (v.y >= 0.0f) ? v.y : 0.01f * v.y;
        v.z = (v.z >= 0.0f) ? v.z : 0.01f * v.z;
        v.w = (v.w >= 0.0f) ? v.w : 0.01f * v.w;
      }
      *(float4*)&Y[(long)gi * D + c0] = v;
    }
  }
}

// ---- BN stats ----
__global__ __launch_bounds__(256) void bn_stats_kernel(const float* __restrict__ Y,
    float* __restrict__ stats) {
  int tid = threadIdx.x;
  int d = tid & 63, q = tid >> 6;
  float s = 0.0f, ss = 0.0f;
  for (int i = blockIdx.x * 4 + q; i < NN; i += gridDim.x * 4) {
    float v = Y[(long)i * D + d];
    s += v;
    ss += v * v;
  }
  __shared__ float Ss[4][64], SSs[4][64];
  Ss[q][d] = s; SSs[q][d] = ss;
  __syncthreads();
  if (q == 0) {
    s  = Ss[0][d] + Ss[1][d] + Ss[2][d] + Ss[3][d];
    ss = SSs[0][d] + SSs[1][d] + SSs[2][d] + SSs[3][d];
    atomicAdd(&stats[d], s);
    atomicAdd(&stats[64 + d], ss);
  }
}

// ---- BN apply + leaky ----
__global__ __launch_bounds__(256) void bn_apply_kernel(const float* __restrict__ Y,
    const float* __restrict__ stats,
    const float* __restrict__ g, const float* __restrict__ b,
    float* __restrict__ Out) {
  int idx = blockIdx.x * 256 + threadIdx.x;
  int i = idx >> 6, d = idx & 63;
  if (i >= NN) return;
  float invn = 1.0f / (float)NN;
  float mu = stats[d] * invn;
  float var = fmaxf(stats[64 + d] * invn - mu * mu, 0.0f);
  float sc = g[d] * rsqrtf(var + BN_EPS);
  float v = sc * (Y[(long)i * D + d] - mu) + b[d];
  v = (v >= 0.0f) ? v : 0.01f * v;
  Out[(long)i * D + d] = v;
}

// ---- fc2 ----
__global__ __launch_bounds__(256) void fc2_kernel(const float* __restrict__ H,
    const float* __restrict__ W, const float* __restrict__ b,
    float* __restrict__ out) {
  int tid = threadIdx.x;
  int k = tid & 63, q = tid >> 6;
  int i = blockIdx.x * 4 + q;
  float v = (i < NN) ? H[(long)i * D + k] * W[k] : 0.0f;
  #pragma unroll
  for (int off = 32; off > 0; off >>= 1)
    v += __shfl_down(v, off);
  if (k == 0 && i < NN) {
    float x = v + b[0];
    out[i] = 1.0f / (1.0f + __expf(-x));
  }
}

extern "C" void kernel_launch(void* const* d_in, const int* in_sizes, int n_in,
                              void* d_out, int out_size, void* d_ws, size_t ws_size,
                              hipStream_t stream) {
  const int*   node_deg   = (const int*)d_in[0];
  const int*   edge_index = (const int*)d_in[1];
  const float* embed      = (const float*)d_in[2];
  const float* eps        = (const float*)d_in[3];
  const float* W1         = (const float*)d_in[4];
  const float* b1         = (const float*)d_in[5];
  const float* W2         = (const float*)d_in[6];
  const float* b2         = (const float*)d_in[7];
  const float* bn_g       = (const float*)d_in[8];
  const float* bn_b       = (const float*)d_in[9];
  const float* fc_W1      = (const float*)d_in[10];
  const float* fc_b1      = (const float*)d_in[11];
  const float* fc_bn_g    = (const float*)d_in[12];
  const float* fc_bn_b    = (const float*)d_in[13];
  const float* fc_W2      = (const float*)d_in[14];
  const float* fc_b2      = (const float*)d_in[15];

  // workspace: 4x[N,64] f32 (tmp aliased onto agg) + stats + sort arrays
  float* cur    = (float*)d_ws;                 // [N,64]
  float* nxt    = cur + (long)NN * D;           // [N,64]
  float* fc1acc = nxt + (long)NN * D;           // [N,64]
  float* agg    = fc1acc + (long)NN * D;        // [N,64]  (also "tmp")
  float* tmp    = agg;                          // alias: safe, row-local gemm
  float* stats  = agg + (long)NN * D;           // [128]
  int*   cnt    = (int*)(stats + 128);          // [NN]
  int*   csroff = cnt + NN;                     // [NN+1]
  int*   bsum   = csroff + NN + 1;              // [512]
  int*   csrsrc = bsum + 512;                   // [NE]
  int*   rec    = csrsrc + NE;                  // [NE] packed records
  int*   S      = rec + NE;                     // [NP*392]

  const int rowBlocks  = NN / 4;                 // 25000
  const int gemmBlocks = (NN + 63) / 64;         // 1563

  // ---- build CSR (by dst) via private-region bucket sort ----
  hipMemsetAsync(cnt, 0, (size_t)NN * sizeof(int), stream);
  bucket_kernel<<<NP, 256, 0, stream>>>(edge_index, rec, S, cnt);
  scan1_kernel<<<SCAN_B, 256, 0, stream>>>(cnt, bsum);
  scan2_kernel<<<1, 512, 0, stream>>>(bsum);
  scan3_kernel<<<SCAN_B, 256, 0, stream>>>(cnt, bsum, csroff);
  sort_kernel<<<NB, 256, 0, stream>>>(rec, S, csroff, csrsrc);

  // ---- embedding + fc1 contribution of slice 0 ----
  embed_kernel<<<rowBlocks, 256, 0, stream>>>(node_deg, embed, cur);
  gemm64_kernel<<<gemmBlocks, 256, 0, stream>>>(cur, nullptr, nullptr, 0,
      fc_W1, fc_b1, fc1acc, 0, 0);

  for (int l = 0; l < 3; ++l) {
    agg_kernel<<<rowBlocks, 256, 0, stream>>>(csroff, csrsrc, cur, agg);
    // tmp(=agg) = leaky(((1+eps)x + agg) @ W1 + b1)   [in-place, row-local]
    gemm64_kernel<<<gemmBlocks, 256, 0, stream>>>(cur, agg, eps, l,
        W1 + (long)l * D * D, b1 + (long)l * D, tmp, 1, 0);
    // nxt = tmp @ W2 + b2  (pre-BN)
    gemm64_kernel<<<gemmBlocks, 256, 0, stream>>>(tmp, nullptr, nullptr, 0,
        W2 + (long)l * D * D, b2 + (long)l * D, nxt, 0, 0);
    hipMemsetAsync(stats, 0, 128 * sizeof(float), stream);
    bn_stats_kernel<<<256, 256, 0, stream>>>(nxt, stats);
    bn_apply_kernel<<<rowBlocks, 256, 0, stream>>>(nxt, stats,
        bn_g + (long)l * D, bn_b + (long)l * D, nxt);
    // fc1acc += nxt @ fc_W1[(l+1)*64 : (l+2)*64, :]
    gemm64_kernel<<<gemmBlocks, 256, 0, stream>>>(nxt, nullptr, nullptr, 0,
        fc_W1 + (long)(l + 1) * D * D, nullptr, fc1acc, 0, 1);
    float* t2 = cur; cur = nxt; nxt = t2;  // swap
  }

  // ---- fc1 BN + leaky -> tmp; fc2 + sigmoid -> out ----
  hipMemsetAsync(stats, 0, 128 * sizeof(float), stream);
  bn_stats_kernel<<<256, 256, 0, stream>>>(fc1acc, stats);
  bn_apply_kernel<<<rowBlocks, 256, 0, stream>>>(fc1acc, stats,
      fc_bn_g, fc_bn_b, tmp);
  fc2_kernel<<<rowBlocks, 256, 0, stream>>>(tmp, fc_W2, fc_b2, (float*)d_out);
}

// Round 6
// 1019.597 us; speedup vs baseline: 2.7852x; 1.0321x over previous
//
#include <hip/hip_runtime.h>
#include <hip/hip_bf16.h>

#define NN 100000
#define NE 3200000
#define D 64
#define BN_EPS 1e-5f

#define NP 512       // producer blocks
#define CHUNK 6250   // edges per producer (512*6250 = 3.2M exactly)
#define NB 391       // dst buckets of 256 nodes (391*256 = 100096 >= NN)

// ---- embedding gather: cur = embed_deg[node_deg]  [N,64] ----
__global__ __launch_bounds__(256) void embed_kernel(const int* __restrict__ deg,
    const float* __restrict__ emb, float* __restrict__ cur) {
  int idx = blockIdx.x * 256 + threadIdx.x;
  int i = idx >> 6, d = idx & 63;
  if (i < NN) cur[(long)i * D + d] = emb[(long)deg[i] * D + d];
}

// ---- producer: bucket edges into private per-block regions (packed records)
//      rec = src | (dstLocal << 17). No global atomics.
__global__ __launch_bounds__(256) void bucket_kernel(const int* __restrict__ ei,
    int* __restrict__ rec, int* __restrict__ S) {
  __shared__ int cntL[392];     // bucket counts (padded)
  __shared__ int curL[392];     // bucket cursors
  __shared__ int scanbuf[256];
  int t = threadIdx.x;
  int p = blockIdx.x;
  int e0 = p * CHUNK;
  cntL[t] = 0;
  if (t < 136) cntL[256 + t] = 0;
  __syncthreads();
  // pass 1: bucket histogram (LDS only)
  for (int e = t; e < CHUNK; e += 256) {
    int dd = ei[NE + e0 + e];
    atomicAdd(&cntL[(unsigned)dd >> 8], 1);
  }
  __syncthreads();
  // exclusive scan over 392 counters: 196 thread-pairs + block scan
  int a0 = 0, a1 = 0;
  if (t < 196) { a0 = cntL[2 * t]; a1 = cntL[2 * t + 1]; }
  int s = a0 + a1;
  scanbuf[t] = s;
  __syncthreads();
  for (int off = 1; off < 256; off <<= 1) {
    int x = (t >= off) ? scanbuf[t - off] : 0;
    __syncthreads();
    scanbuf[t] += x;
    __syncthreads();
  }
  int ex = scanbuf[t] - s;   // exclusive over pair sums
  if (t < 196) {
    curL[2 * t]     = ex;
    curL[2 * t + 1] = ex + a0;
    S[p * 392 + 2 * t]     = e0 + ex;
    S[p * 392 + 2 * t + 1] = e0 + ex + a0;   // t=195 -> S[p][391] = e0+6250
  }
  __syncthreads();
  // pass 2: scatter packed records into MY private region (write-amp ~1)
  for (int e = t; e < CHUNK; e += 256) {
    int ss = ei[e0 + e];
    int dd = ei[NE + e0 + e];
    int b = (unsigned)dd >> 8;
    int pos = atomicAdd(&curL[b], 1);
    rec[e0 + pos] = ss | ((dd & 255) << 17);
  }
}

// ---- bucket totals from S boundaries: bsum[B] = sum_p (S[p][B+1]-S[p][B]) ----
__global__ __launch_bounds__(256) void bucketsum_kernel(const int* __restrict__ S,
    int* __restrict__ bsum) {
  __shared__ int sh[256];
  int B = blockIdx.x;
  int t = threadIdx.x;
  int c = 0;
  for (int p = t; p < NP; p += 256)
    c += S[p * 392 + B + 1] - S[p * 392 + B];
  sh[t] = c;
  __syncthreads();
  for (int o = 128; o > 0; o >>= 1) {
    if (t < o) sh[t] += sh[t + o];
    __syncthreads();
  }
  if (t == 0) bsum[B] = sh[0];
}

// ---- exclusive scan of 391 bucket totals ----
__global__ __launch_bounds__(512) void scan2_kernel(int* __restrict__ bsum) {
  __shared__ int sh[512];
  int t = threadIdx.x;
  int v = (t < NB) ? bsum[t] : 0;
  sh[t] = v;
  __syncthreads();
  for (int o = 1; o < 512; o <<= 1) {
    int x = (t >= o) ? sh[t - o] : 0;
    __syncthreads();
    sh[t] += x;
    __syncthreads();
  }
  if (t < NB) bsum[t] = sh[t] - v;   // exclusive
}

// ---- sorter: one block per bucket. Builds per-node histogram from records,
//      derives csroff for its 256 nodes, scatters csrsrc (block-owned range).
__global__ __launch_bounds__(256) void sort_kernel(const int* __restrict__ rec,
    const int* __restrict__ S, const int* __restrict__ bsum,
    int* __restrict__ csroff, int* __restrict__ csrsrc) {
  __shared__ int cntL[256];
  __shared__ int curL[256];
  int t = threadIdx.x;
  int B = blockIdx.x;
  cntL[t] = 0;
  __syncthreads();
  int lane = t & 63, wq = t >> 6;
  // pass 1: per-node (dstLocal) histogram
  for (int p = wq; p < NP; p += 4) {
    int s0 = S[p * 392 + B], s1 = S[p * 392 + B + 1];
    for (int e = s0 + lane; e < s1; e += 64)
      atomicAdd(&cntL[(unsigned)rec[e] >> 17], 1);
  }
  __syncthreads();
  // exclusive scan of 256 counters
  int v = cntL[t];
  curL[t] = v;
  __syncthreads();
  for (int o = 1; o < 256; o <<= 1) {
    int x = (t >= o) ? curL[t - o] : 0;
    __syncthreads();
    curL[t] += x;
    __syncthreads();
  }
  int excl = curL[t] - v;
  int b0 = bsum[B];
  int node = B * 256 + t;
  if (node <= NN) csroff[node] = b0 + excl;   // bucket 390/t=160 writes csroff[NN]=NE
  __syncthreads();
  curL[t] = b0 + excl;
  __syncthreads();
  // pass 2: scatter records into block-owned csr range
  for (int p = wq; p < NP; p += 4) {
    int s0 = S[p * 392 + B], s1 = S[p * 392 + B + 1];
    for (int e = s0 + lane; e < s1; e += 64) {
      int r = rec[e];
      int pos = atomicAdd(&curL[(unsigned)r >> 17], 1);
      csrsrc[pos] = r & 0x1FFFF;
    }
  }
}

// ---- aggregation: agg[i,:] = sum over in-edges of x[src,:]  (wave/node) ----
__global__ __launch_bounds__(256) void agg_kernel(const int* __restrict__ off,
    const int* __restrict__ srcs, const float* __restrict__ x,
    float* __restrict__ agg) {
  int t = threadIdx.x;
  int d = t & 63, q = t >> 6;
  int i = blockIdx.x * 4 + q;
  int e0 = off[i], e1 = off[i + 1];
  float s = 0.0f;
  int e = e0;
  for (; e + 8 <= e1; e += 8) {
    int j0 = srcs[e + 0], j1 = srcs[e + 1], j2 = srcs[e + 2], j3 = srcs[e + 3];
    int j4 = srcs[e + 4], j5 = srcs[e + 5], j6 = srcs[e + 6], j7 = srcs[e + 7];
    float v0 = x[(long)j0 * D + d], v1 = x[(long)j1 * D + d];
    float v2 = x[(long)j2 * D + d], v3 = x[(long)j3 * D + d];
    float v4 = x[(long)j4 * D + d], v5 = x[(long)j5 * D + d];
    float v6 = x[(long)j6 * D + d], v7 = x[(long)j7 * D + d];
    s += ((v0 + v1) + (v2 + v3)) + ((v4 + v5) + (v6 + v7));
  }
  for (; e < e1; e++) s += x[(long)srcs[e] * D + d];
  agg[(long)i * D + d] = s;
}

// ---- 64x64-tiled GEMM (K=64), 4x4 register tile per thread ----
__global__ __launch_bounds__(256) void gemm64_kernel(
    const float* __restrict__ X,
    const float* __restrict__ AGG, const float* __restrict__ epsv, int l,
    const float* __restrict__ W, const float* __restrict__ bias,
    float* Y, int leaky, int accum)
{
  __shared__ float Ws[64][64];     // Ws[k][d]
  __shared__ float XsT[64][64];    // XsT[k][row]
  int t = threadIdx.x;
  int i0 = blockIdx.x * 64;
  float alpha = (AGG != nullptr) ? (1.0f + epsv[l]) : 1.0f;

  {
    int wr = t >> 4;
    int wc = (t & 15) * 4;
    #pragma unroll
    for (int j = 0; j < 4; j++) {
      float4 w4 = *(const float4*)&W[(long)(wr + 16 * j) * D + wc];
      *(float4*)&Ws[wr + 16 * j][wc] = w4;
    }
  }
  {
    int row = t & 63;
    int gi = i0 + row;
    int gis = (gi < NN) ? gi : NN - 1;
    int kb = (t >> 6) * 16;
    #pragma unroll
    for (int j = 0; j < 4; j++) {
      int k = kb + 4 * j;
      float4 xv = *(const float4*)&X[(long)gis * D + k];
      if (AGG) {
        float4 a4 = *(const float4*)&AGG[(long)gis * D + k];
        xv.x = alpha * xv.x + a4.x;
        xv.y = alpha * xv.y + a4.y;
        xv.z = alpha * xv.z + a4.z;
        xv.w = alpha * xv.w + a4.w;
      }
      XsT[k + 0][row] = xv.x;
      XsT[k + 1][row] = xv.y;
      XsT[k + 2][row] = xv.z;
      XsT[k + 3][row] = xv.w;
    }
  }

  int c0 = (t & 15) * 4;
  int r0 = (t >> 4) * 4;
  float4 acc[4];
  if (accum) {
    #pragma unroll
    for (int r = 0; r < 4; r++) {
      int gi = i0 + r0 + r;
      int gis = (gi < NN) ? gi : NN - 1;
      acc[r] = *(const float4*)&Y[(long)gis * D + c0];
    }
  } else {
    float4 b4 = *(const float4*)&bias[c0];
    #pragma unroll
    for (int r = 0; r < 4; r++) acc[r] = b4;
  }
  __syncthreads();

  #pragma unroll 8
  for (int k = 0; k < 64; k++) {
    float4 w4 = *(const float4*)&Ws[k][c0];
    float4 x4 = *(const float4*)&XsT[k][r0];
    acc[0].x += x4.x * w4.x; acc[0].y += x4.x * w4.y;
    acc[0].z += x4.x * w4.z; acc[0].w += x4.x * w4.w;
    acc[1].x += x4.y * w4.x; acc[1].y += x4.y * w4.y;
    acc[1].z += x4.y * w4.z; acc[1].w += x4.y * w4.w;
    acc[2].x += x4.z * w4.x; acc[2].y += x4.z * w4.y;
    acc[2].z += x4.z * w4.z; acc[2].w += x4.z * w4.w;
    acc[3].x += x4.w * w4.x; acc[3].y += x4.w * w4.y;
    acc[3].z += x4.w * w4.z; acc[3].w += x4.w * w4.w;
  }

  #pragma unroll
  for (int r = 0; r < 4; r++) {
    int gi = i0 + r0 + r;
    if (gi < NN) {
      float4 v = acc[r];
      if (leaky) {
        v.x = (v.x >= 0.0f) ? v.x : 0.01f * v.x;
        v.y = (v.y >= 0.0f) ? v.y : 0.01f * v.y;
        v.z = (v.z >= 0.0f) ? v.z : 0.01f * v.z;
        v.w = (v.w >= 0.0f) ? v.w : 0.01f * v.w;
      }
      *(float4*)&Y[(long)gi * D + c0] = v;
    }
  }
}

// ---- BN stats ----
__global__ __launch_bounds__(256) void bn_stats_kernel(const float* __restrict__ Y,
    float* __restrict__ stats) {
  int tid = threadIdx.x;
  int d = tid & 63, q = tid >> 6;
  float s = 0.0f, ss = 0.0f;
  for (int i = blockIdx.x * 4 + q; i < NN; i += gridDim.x * 4) {
    float v = Y[(long)i * D + d];
    s += v;
    ss += v * v;
  }
  __shared__ float Ss[4][64], SSs[4][64];
  Ss[q][d] = s; SSs[q][d] = ss;
  __syncthreads();
  if (q == 0) {
    s  = Ss[0][d] + Ss[1][d] + Ss[2][d] + Ss[3][d];
    ss = SSs[0][d] + SSs[1][d] + SSs[2][d] + SSs[3][d];
    atomicAdd(&stats[d], s);
    atomicAdd(&stats[64 + d], ss);
  }
}

// ---- BN apply + leaky ----
__global__ __launch_bounds__(256) void bn_apply_kernel(const float* __restrict__ Y,
    const float* __restrict__ stats,
    const float* __restrict__ g, const float* __restrict__ b,
    float* __restrict__ Out) {
  int idx = blockIdx.x * 256 + threadIdx.x;
  int i = idx >> 6, d = idx & 63;
  if (i >= NN) return;
  float invn = 1.0f / (float)NN;
  float mu = stats[d] * invn;
  float var = fmaxf(stats[64 + d] * invn - mu * mu, 0.0f);
  float sc = g[d] * rsqrtf(var + BN_EPS);
  float v = sc * (Y[(long)i * D + d] - mu) + b[d];
  v = (v >= 0.0f) ? v : 0.01f * v;
  Out[(long)i * D + d] = v;
}

// ---- fc2 ----
__global__ __launch_bounds__(256) void fc2_kernel(const float* __restrict__ H,
    const float* __restrict__ W, const float* __restrict__ b,
    float* __restrict__ out) {
  int tid = threadIdx.x;
  int k = tid & 63, q = tid >> 6;
  int i = blockIdx.x * 4 + q;
  float v = (i < NN) ? H[(long)i * D + k] * W[k] : 0.0f;
  #pragma unroll
  for (int off = 32; off > 0; off >>= 1)
    v += __shfl_down(v, off);
  if (k == 0 && i < NN) {
    float x = v + b[0];
    out[i] = 1.0f / (1.0f + __expf(-x));
  }
}

extern "C" void kernel_launch(void* const* d_in, const int* in_sizes, int n_in,
                              void* d_out, int out_size, void* d_ws, size_t ws_size,
                              hipStream_t stream) {
  const int*   node_deg   = (const int*)d_in[0];
  const int*   edge_index = (const int*)d_in[1];
  const float* embed      = (const float*)d_in[2];
  const float* eps        = (const float*)d_in[3];
  const float* W1         = (const float*)d_in[4];
  const float* b1         = (const float*)d_in[5];
  const float* W2         = (const float*)d_in[6];
  const float* b2         = (const float*)d_in[7];
  const float* bn_g       = (const float*)d_in[8];
  const float* bn_b       = (const float*)d_in[9];
  const float* fc_W1      = (const float*)d_in[10];
  const float* fc_b1      = (const float*)d_in[11];
  const float* fc_bn_g    = (const float*)d_in[12];
  const float* fc_bn_b    = (const float*)d_in[13];
  const float* fc_W2      = (const float*)d_in[14];
  const float* fc_b2      = (const float*)d_in[15];

  // workspace: 4x[N,64] f32 (tmp aliased onto agg) + stats + sort arrays
  float* cur    = (float*)d_ws;                 // [N,64]
  float* nxt    = cur + (long)NN * D;           // [N,64]
  float* fc1acc = nxt + (long)NN * D;           // [N,64]
  float* agg    = fc1acc + (long)NN * D;        // [N,64]  (also "tmp")
  float* tmp    = agg;                          // alias: safe, row-local gemm
  float* stats  = agg + (long)NN * D;           // [128]
  int*   csroff = (int*)(stats + 128);          // [NN+1]
  int*   bsum   = csroff + NN + 1;              // [512]
  int*   csrsrc = bsum + 512;                   // [NE]
  int*   rec    = csrsrc + NE;                  // [NE] packed records
  int*   S      = rec + NE;                     // [NP*392]

  const int rowBlocks  = NN / 4;                 // 25000
  const int gemmBlocks = (NN + 63) / 64;         // 1563

  // ---- build CSR (by dst): private-region bucket sort, no global atomics ----
  bucket_kernel<<<NP, 256, 0, stream>>>(edge_index, rec, S);
  bucketsum_kernel<<<NB, 256, 0, stream>>>(S, bsum);
  scan2_kernel<<<1, 512, 0, stream>>>(bsum);
  sort_kernel<<<NB, 256, 0, stream>>>(rec, S, bsum, csroff, csrsrc);

  // ---- embedding + fc1 contribution of slice 0 ----
  embed_kernel<<<rowBlocks, 256, 0, stream>>>(node_deg, embed, cur);
  gemm64_kernel<<<gemmBlocks, 256, 0, stream>>>(cur, nullptr, nullptr, 0,
      fc_W1, fc_b1, fc1acc, 0, 0);

  for (int l = 0; l < 3; ++l) {
    agg_kernel<<<rowBlocks, 256, 0, stream>>>(csroff, csrsrc, cur, agg);
    // tmp(=agg) = leaky(((1+eps)x + agg) @ W1 + b1)   [in-place, row-local]
    gemm64_kernel<<<gemmBlocks, 256, 0, stream>>>(cur, agg, eps, l,
        W1 + (long)l * D * D, b1 + (long)l * D, tmp, 1, 0);
    // nxt = tmp @ W2 + b2  (pre-BN)
    gemm64_kernel<<<gemmBlocks, 256, 0, stream>>>(tmp, nullptr, nullptr, 0,
        W2 + (long)l * D * D, b2 + (long)l * D, nxt, 0, 0);
    hipMemsetAsync(stats, 0, 128 * sizeof(float), stream);
    bn_stats_kernel<<<256, 256, 0, stream>>>(nxt, stats);
    bn_apply_kernel<<<rowBlocks, 256, 0, stream>>>(nxt, stats,
        bn_g + (long)l * D, bn_b + (long)l * D, nxt);
    // fc1acc += nxt @ fc_W1[(l+1)*64 : (l+2)*64, :]
    gemm64_kernel<<<gemmBlocks, 256, 0, stream>>>(nxt, nullptr, nullptr, 0,
        fc_W1 + (long)(l + 1) * D * D, nullptr, fc1acc, 0, 1);
    float* t2 = cur; cur = nxt; nxt = t2;  // swap
  }

  // ---- fc1 BN + leaky -> tmp; fc2 + sigmoid -> out ----
  hipMemsetAsync(stats, 0, 128 * sizeof(float), stream);
  bn_stats_kernel<<<256, 256, 0, stream>>>(fc1acc, stats);
  bn_apply_kernel<<<rowBlocks, 256, 0, stream>>>(fc1acc, stats,
      fc_bn_g, fc_bn_b, tmp);
  fc2_kernel<<<rowBlocks, 256, 0, stream>>>(tmp, fc_W2, fc_b2, (float*)d_out);
}

// Round 7
// 901.713 us; speedup vs baseline: 3.1493x; 1.1307x over previous
//
#include <hip/hip_runtime.h>
#include <hip/hip_bf16.h>

#define NN 100000
#define NE 3200000
#define D 64
#define BN_EPS 1e-5f

#define NP 512       // producer blocks
#define CHUNK 6250   // edges per producer (512*6250 = 3.2M exactly)
#define NB 391       // dst buckets of 256 nodes (391*256 = 100096 >= NN)

// ---- embedding gather: cur = embed_deg[node_deg]  [N,64] ----
__global__ __launch_bounds__(256) void embed_kernel(const int* __restrict__ deg,
    const float* __restrict__ emb, float* __restrict__ cur) {
  int idx = blockIdx.x * 256 + threadIdx.x;
  int i = idx >> 6, d = idx & 63;
  if (i < NN) cur[(long)i * D + d] = emb[(long)deg[i] * D + d];
}

// ---- producer: bucket edges into private per-block regions (packed records)
//      rec = src | (dstLocal << 17). No global atomics.
__global__ __launch_bounds__(256) void bucket_kernel(const int* __restrict__ ei,
    int* __restrict__ rec, int* __restrict__ S) {
  __shared__ int cntL[392];     // bucket counts (padded)
  __shared__ int curL[392];     // bucket cursors
  __shared__ int scanbuf[256];
  int t = threadIdx.x;
  int p = blockIdx.x;
  int e0 = p * CHUNK;
  cntL[t] = 0;
  if (t < 136) cntL[256 + t] = 0;
  __syncthreads();
  // pass 1: bucket histogram (LDS only)
  for (int e = t; e < CHUNK; e += 256) {
    int dd = ei[NE + e0 + e];
    atomicAdd(&cntL[(unsigned)dd >> 8], 1);
  }
  __syncthreads();
  // exclusive scan over 392 counters: 196 thread-pairs + block scan
  int a0 = 0, a1 = 0;
  if (t < 196) { a0 = cntL[2 * t]; a1 = cntL[2 * t + 1]; }
  int s = a0 + a1;
  scanbuf[t] = s;
  __syncthreads();
  for (int off = 1; off < 256; off <<= 1) {
    int x = (t >= off) ? scanbuf[t - off] : 0;
    __syncthreads();
    scanbuf[t] += x;
    __syncthreads();
  }
  int ex = scanbuf[t] - s;   // exclusive over pair sums
  if (t < 196) {
    curL[2 * t]     = ex;
    curL[2 * t + 1] = ex + a0;
    S[p * 392 + 2 * t]     = e0 + ex;
    S[p * 392 + 2 * t + 1] = e0 + ex + a0;   // t=195 -> S[p][391] = e0+6250
  }
  __syncthreads();
  // pass 2: scatter packed records into MY private region (write-amp ~1)
  for (int e = t; e < CHUNK; e += 256) {
    int ss = ei[e0 + e];
    int dd = ei[NE + e0 + e];
    int b = (unsigned)dd >> 8;
    int pos = atomicAdd(&curL[b], 1);
    rec[e0 + pos] = ss | ((dd & 255) << 17);
  }
}

// ---- bucket totals from S boundaries: bsum[B] = sum_p (S[p][B+1]-S[p][B]) ----
__global__ __launch_bounds__(256) void bucketsum_kernel(const int* __restrict__ S,
    int* __restrict__ bsum) {
  __shared__ int sh[256];
  int B = blockIdx.x;
  int t = threadIdx.x;
  int c = 0;
  for (int p = t; p < NP; p += 256)
    c += S[p * 392 + B + 1] - S[p * 392 + B];
  sh[t] = c;
  __syncthreads();
  for (int o = 128; o > 0; o >>= 1) {
    if (t < o) sh[t] += sh[t + o];
    __syncthreads();
  }
  if (t == 0) bsum[B] = sh[0];
}

// ---- exclusive scan of 391 bucket totals ----
__global__ __launch_bounds__(512) void scan2_kernel(int* __restrict__ bsum) {
  __shared__ int sh[512];
  int t = threadIdx.x;
  int v = (t < NB) ? bsum[t] : 0;
  sh[t] = v;
  __syncthreads();
  for (int o = 1; o < 512; o <<= 1) {
    int x = (t >= o) ? sh[t - o] : 0;
    __syncthreads();
    sh[t] += x;
    __syncthreads();
  }
  if (t < NB) bsum[t] = sh[t] - v;   // exclusive
}

// ---- sorter: one block per bucket, 512 threads, 16-lane segment groups.
//      Builds per-node histogram from records, derives csroff, scatters csrsrc.
__global__ __launch_bounds__(512) void sort_kernel(const int* __restrict__ rec,
    const int* __restrict__ S, const int* __restrict__ bsum,
    int* __restrict__ csroff, int* __restrict__ csrsrc) {
  __shared__ int cntL[256];
  __shared__ int curL[256];
  int t = threadIdx.x;
  int B = blockIdx.x;
  if (t < 256) cntL[t] = 0;
  __syncthreads();
  int lane = t & 15;          // 16-lane group: matches ~16-record avg segment
  int g = t >> 4;             // 32 groups per block
  // pass 1: per-node (dstLocal) histogram
  for (int p = g; p < NP; p += 32) {
    int s0 = S[p * 392 + B], s1 = S[p * 392 + B + 1];
    for (int e = s0 + lane; e < s1; e += 16)
      atomicAdd(&cntL[(unsigned)rec[e] >> 17], 1);
  }
  __syncthreads();
  // exclusive scan of 256 counters (threads >=256 just hit the barriers)
  int v = 0;
  if (t < 256) { v = cntL[t]; curL[t] = v; }
  __syncthreads();
  for (int o = 1; o < 256; o <<= 1) {
    int x = 0;
    if (t < 256 && t >= o) x = curL[t - o];
    __syncthreads();
    if (t < 256) curL[t] += x;
    __syncthreads();
  }
  int b0 = bsum[B];
  if (t < 256) {
    int excl = curL[t] - v;
    int node = B * 256 + t;
    if (node <= NN) csroff[node] = b0 + excl;  // bucket 390/t=160 -> csroff[NN]=NE
  }
  __syncthreads();
  if (t < 256) curL[t] = b0 + (curL[t] - v);
  __syncthreads();
  // pass 2: scatter records into block-owned csr range
  for (int p = g; p < NP; p += 32) {
    int s0 = S[p * 392 + B], s1 = S[p * 392 + B + 1];
    for (int e = s0 + lane; e < s1; e += 16) {
      int r = rec[e];
      int pos = atomicAdd(&curL[(unsigned)r >> 17], 1);
      csrsrc[pos] = r & 0x1FFFF;
    }
  }
}

// ---- aggregation: agg[i,:] = sum over in-edges of x[src,:]  (wave/node) ----
__global__ __launch_bounds__(256) void agg_kernel(const int* __restrict__ off,
    const int* __restrict__ srcs, const float* __restrict__ x,
    float* __restrict__ agg) {
  int t = threadIdx.x;
  int d = t & 63, q = t >> 6;
  int i = blockIdx.x * 4 + q;
  int e0 = off[i], e1 = off[i + 1];
  float s = 0.0f;
  int e = e0;
  for (; e + 8 <= e1; e += 8) {
    int j0 = srcs[e + 0], j1 = srcs[e + 1], j2 = srcs[e + 2], j3 = srcs[e + 3];
    int j4 = srcs[e + 4], j5 = srcs[e + 5], j6 = srcs[e + 6], j7 = srcs[e + 7];
    float v0 = x[(long)j0 * D + d], v1 = x[(long)j1 * D + d];
    float v2 = x[(long)j2 * D + d], v3 = x[(long)j3 * D + d];
    float v4 = x[(long)j4 * D + d], v5 = x[(long)j5 * D + d];
    float v6 = x[(long)j6 * D + d], v7 = x[(long)j7 * D + d];
    s += ((v0 + v1) + (v2 + v3)) + ((v4 + v5) + (v6 + v7));
  }
  for (; e < e1; e++) s += x[(long)srcs[e] * D + d];
  agg[(long)i * D + d] = s;
}

// ---- 64x64-tiled GEMM (K=64), 4x4 register tile per thread ----
__global__ __launch_bounds__(256) void gemm64_kernel(
    const float* __restrict__ X,
    const float* __restrict__ AGG, const float* __restrict__ epsv, int l,
    const float* __restrict__ W, const float* __restrict__ bias,
    float* Y, int leaky, int accum)
{
  __shared__ float Ws[64][64];     // Ws[k][d]
  __shared__ float XsT[64][64];    // XsT[k][row]
  int t = threadIdx.x;
  int i0 = blockIdx.x * 64;
  float alpha = (AGG != nullptr) ? (1.0f + epsv[l]) : 1.0f;

  {
    int wr = t >> 4;
    int wc = (t & 15) * 4;
    #pragma unroll
    for (int j = 0; j < 4; j++) {
      float4 w4 = *(const float4*)&W[(long)(wr + 16 * j) * D + wc];
      *(float4*)&Ws[wr + 16 * j][wc] = w4;
    }
  }
  {
    int row = t & 63;
    int gi = i0 + row;
    int gis = (gi < NN) ? gi : NN - 1;
    int kb = (t >> 6) * 16;
    #pragma unroll
    for (int j = 0; j < 4; j++) {
      int k = kb + 4 * j;
      float4 xv = *(const float4*)&X[(long)gis * D + k];
      if (AGG) {
        float4 a4 = *(const float4*)&AGG[(long)gis * D + k];
        xv.x = alpha * xv.x + a4.x;
        xv.y = alpha * xv.y + a4.y;
        xv.z = alpha * xv.z + a4.z;
        xv.w = alpha * xv.w + a4.w;
      }
      XsT[k + 0][row] = xv.x;
      XsT[k + 1][row] = xv.y;
      XsT[k + 2][row] = xv.z;
      XsT[k + 3][row] = xv.w;
    }
  }

  int c0 = (t & 15) * 4;
  int r0 = (t >> 4) * 4;
  float4 acc[4];
  if (accum) {
    #pragma unroll
    for (int r = 0; r < 4; r++) {
      int gi = i0 + r0 + r;
      int gis = (gi < NN) ? gi : NN - 1;
      acc[r] = *(const float4*)&Y[(long)gis * D + c0];
    }
  } else {
    float4 b4 = *(const float4*)&bias[c0];
    #pragma unroll
    for (int r = 0; r < 4; r++) acc[r] = b4;
  }
  __syncthreads();

  #pragma unroll 8
  for (int k = 0; k < 64; k++) {
    float4 w4 = *(const float4*)&Ws[k][c0];
    float4 x4 = *(const float4*)&XsT[k][r0];
    acc[0].x += x4.x * w4.x; acc[0].y += x4.x * w4.y;
    acc[0].z += x4.x * w4.z; acc[0].w += x4.x * w4.w;
    acc[1].x += x4.y * w4.x; acc[1].y += x4.y * w4.y;
    acc[1].z += x4.y * w4.z; acc[1].w += x4.y * w4.w;
    acc[2].x += x4.z * w4.x; acc[2].y += x4.z * w4.y;
    acc[2].z += x4.z * w4.z; acc[2].w += x4.z * w4.w;
    acc[3].x += x4.w * w4.x; acc[3].y += x4.w * w4.y;
    acc[3].z += x4.w * w4.z; acc[3].w += x4.w * w4.w;
  }

  #pragma unroll
  for (int r = 0; r < 4; r++) {
    int gi = i0 + r0 + r;
    if (gi < NN) {
      float4 v = acc[r];
      if (leaky) {
        v.x = (v.x >= 0.0f) ? v.x : 0.01f * v.x;
        v.y = (v.y >= 0.0f) ? v.y : 0.01f * v.y;
        v.z = (v.z >= 0.0f) ? v.z : 0.01f * v.z;
        v.w = (v.w >= 0.0f) ? v.w : 0.01f * v.w;
      }
      *(float4*)&Y[(long)gi * D + c0] = v;
    }
  }
}

// ---- BN stats ----
__global__ __launch_bounds__(256) void bn_stats_kernel(const float* __restrict__ Y,
    float* __restrict__ stats) {
  int tid = threadIdx.x;
  int d = tid & 63, q = tid >> 6;
  float s = 0.0f, ss = 0.0f;
  for (int i = blockIdx.x * 4 + q; i < NN; i += gridDim.x * 4) {
    float v = Y[(long)i * D + d];
    s += v;
    ss += v * v;
  }
  __shared__ float Ss[4][64], SSs[4][64];
  Ss[q][d] = s; SSs[q][d] = ss;
  __syncthreads();
  if (q == 0) {
    s  = Ss[0][d] + Ss[1][d] + Ss[2][d] + Ss[3][d];
    ss = SSs[0][d] + SSs[1][d] + SSs[2][d] + SSs[3][d];
    atomicAdd(&stats[d], s);
    atomicAdd(&stats[64 + d], ss);
  }
}

// ---- BN apply + leaky ----
__global__ __launch_bounds__(256) void bn_apply_kernel(const float* __restrict__ Y,
    const float* __restrict__ stats,
    const float* __restrict__ g, const float* __restrict__ b,
    float* __restrict__ Out) {
  int idx = blockIdx.x * 256 + threadIdx.x;
  int i = idx >> 6, d = idx & 63;
  if (i >= NN) return;
  float invn = 1.0f / (float)NN;
  float mu = stats[d] * invn;
  float var = fmaxf(stats[64 + d] * invn - mu * mu, 0.0f);
  float sc = g[d] * rsqrtf(var + BN_EPS);
  float v = sc * (Y[(long)i * D + d] - mu) + b[d];
  v = (v >= 0.0f) ? v : 0.01f * v;
  Out[(long)i * D + d] = v;
}

// ---- fc2 ----
__global__ __launch_bounds__(256) void fc2_kernel(const float* __restrict__ H,
    const float* __restrict__ W, const float* __restrict__ b,
    float* __restrict__ out) {
  int tid = threadIdx.x;
  int k = tid & 63, q = tid >> 6;
  int i = blockIdx.x * 4 + q;
  float v = (i < NN) ? H[(long)i * D + k] * W[k] : 0.0f;
  #pragma unroll
  for (int off = 32; off > 0; off >>= 1)
    v += __shfl_down(v, off);
  if (k == 0 && i < NN) {
    float x = v + b[0];
    out[i] = 1.0f / (1.0f + __expf(-x));
  }
}

extern "C" void kernel_launch(void* const* d_in, const int* in_sizes, int n_in,
                              void* d_out, int out_size, void* d_ws, size_t ws_size,
                              hipStream_t stream) {
  const int*   node_deg   = (const int*)d_in[0];
  const int*   edge_index = (const int*)d_in[1];
  const float* embed      = (const float*)d_in[2];
  const float* eps        = (const float*)d_in[3];
  const float* W1         = (const float*)d_in[4];
  const float* b1         = (const float*)d_in[5];
  const float* W2         = (const float*)d_in[6];
  const float* b2         = (const float*)d_in[7];
  const float* bn_g       = (const float*)d_in[8];
  const float* bn_b       = (const float*)d_in[9];
  const float* fc_W1      = (const float*)d_in[10];
  const float* fc_b1      = (const float*)d_in[11];
  const float* fc_bn_g    = (const float*)d_in[12];
  const float* fc_bn_b    = (const float*)d_in[13];
  const float* fc_W2      = (const float*)d_in[14];
  const float* fc_b2      = (const float*)d_in[15];

  // workspace: 4x[N,64] f32 (tmp aliased onto agg) + stats + sort arrays
  float* cur    = (float*)d_ws;                 // [N,64]
  float* nxt    = cur + (long)NN * D;           // [N,64]
  float* fc1acc = nxt + (long)NN * D;           // [N,64]
  float* agg    = fc1acc + (long)NN * D;        // [N,64]  (also "tmp")
  float* tmp    = agg;                          // alias: safe, row-local gemm
  float* stats  = agg + (long)NN * D;           // [128]
  int*   csroff = (int*)(stats + 128);          // [NN+1]
  int*   bsum   = csroff + NN + 1;              // [512]
  int*   csrsrc = bsum + 512;                   // [NE]
  int*   rec    = csrsrc + NE;                  // [NE] packed records
  int*   S      = rec + NE;                     // [NP*392]

  const int rowBlocks  = NN / 4;                 // 25000
  const int gemmBlocks = (NN + 63) / 64;         // 1563

  // ---- build CSR (by dst): private-region bucket sort, no global atomics ----
  bucket_kernel<<<NP, 256, 0, stream>>>(edge_index, rec, S);
  bucketsum_kernel<<<NB, 256, 0, stream>>>(S, bsum);
  scan2_kernel<<<1, 512, 0, stream>>>(bsum);
  sort_kernel<<<NB, 512, 0, stream>>>(rec, S, bsum, csroff, csrsrc);

  // ---- embedding + fc1 contribution of slice 0 ----
  embed_kernel<<<rowBlocks, 256, 0, stream>>>(node_deg, embed, cur);
  gemm64_kernel<<<gemmBlocks, 256, 0, stream>>>(cur, nullptr, nullptr, 0,
      fc_W1, fc_b1, fc1acc, 0, 0);

  for (int l = 0; l < 3; ++l) {
    agg_kernel<<<rowBlocks, 256, 0, stream>>>(csroff, csrsrc, cur, agg);
    // tmp(=agg) = leaky(((1+eps)x + agg) @ W1 + b1)   [in-place, row-local]
    gemm64_kernel<<<gemmBlocks, 256, 0, stream>>>(cur, agg, eps, l,
        W1 + (long)l * D * D, b1 + (long)l * D, tmp, 1, 0);
    // nxt = tmp @ W2 + b2  (pre-BN)
    gemm64_kernel<<<gemmBlocks, 256, 0, stream>>>(tmp, nullptr, nullptr, 0,
        W2 + (long)l * D * D, b2 + (long)l * D, nxt, 0, 0);
    hipMemsetAsync(stats, 0, 128 * sizeof(float), stream);
    bn_stats_kernel<<<256, 256, 0, stream>>>(nxt, stats);
    bn_apply_kernel<<<rowBlocks, 256, 0, stream>>>(nxt, stats,
        bn_g + (long)l * D, bn_b + (long)l * D, nxt);
    // fc1acc += nxt @ fc_W1[(l+1)*64 : (l+2)*64, :]
    gemm64_kernel<<<gemmBlocks, 256, 0, stream>>>(nxt, nullptr, nullptr, 0,
        fc_W1 + (long)(l + 1) * D * D, nullptr, fc1acc, 0, 1);
    float* t2 = cur; cur = nxt; nxt = t2;  // swap
  }

  // ---- fc1 BN + leaky -> tmp; fc2 + sigmoid -> out ----
  hipMemsetAsync(stats, 0, 128 * sizeof(float), stream);
  bn_stats_kernel<<<256, 256, 0, stream>>>(fc1acc, stats);
  bn_apply_kernel<<<rowBlocks, 256, 0, stream>>>(fc1acc, stats,
      fc_bn_g, fc_bn_b, tmp);
  fc2_kernel<<<rowBlocks, 256, 0, stream>>>(tmp, fc_W2, fc_b2, (float*)d_out);
}

// Round 8
// 867.060 us; speedup vs baseline: 3.2751x; 1.0400x over previous
//
#include <hip/hip_runtime.h>
#include <hip/hip_bf16.h>

#define NN 100000
#define NE 3200000
#define D 64
#define BN_EPS 1e-5f

#define NP 512       // producer blocks
#define CHUNK 6250   // edges per producer (512*6250 = 3.2M exactly)
#define NB 391       // dst buckets of 256 nodes (391*256 = 100096 >= NN)

typedef __hip_bfloat16 bf16;

// ---- embedding gather: cur = embed_deg[node_deg]; xh = bf16(cur) ----
__global__ __launch_bounds__(256) void embed_kernel(const int* __restrict__ deg,
    const float* __restrict__ emb, float* __restrict__ cur,
    bf16* __restrict__ xh) {
  int idx = blockIdx.x * 256 + threadIdx.x;
  int i = idx >> 6, d = idx & 63;
  if (i < NN) {
    float v = emb[(long)deg[i] * D + d];
    cur[(long)i * D + d] = v;
    xh[(long)i * D + d] = __float2bfloat16(v);
  }
}

// ---- producer: bucket edges into private per-block regions (packed records)
//      rec = src | (dstLocal << 17). No global atomics.
__global__ __launch_bounds__(256) void bucket_kernel(const int* __restrict__ ei,
    int* __restrict__ rec, int* __restrict__ S) {
  __shared__ int cntL[392];     // bucket counts (padded)
  __shared__ int curL[392];     // bucket cursors
  __shared__ int scanbuf[256];
  int t = threadIdx.x;
  int p = blockIdx.x;
  int e0 = p * CHUNK;
  cntL[t] = 0;
  if (t < 136) cntL[256 + t] = 0;
  __syncthreads();
  // pass 1: bucket histogram (LDS only)
  for (int e = t; e < CHUNK; e += 256) {
    int dd = ei[NE + e0 + e];
    atomicAdd(&cntL[(unsigned)dd >> 8], 1);
  }
  __syncthreads();
  // exclusive scan over 392 counters: 196 thread-pairs + block scan
  int a0 = 0, a1 = 0;
  if (t < 196) { a0 = cntL[2 * t]; a1 = cntL[2 * t + 1]; }
  int s = a0 + a1;
  scanbuf[t] = s;
  __syncthreads();
  for (int off = 1; off < 256; off <<= 1) {
    int x = (t >= off) ? scanbuf[t - off] : 0;
    __syncthreads();
    scanbuf[t] += x;
    __syncthreads();
  }
  int ex = scanbuf[t] - s;   // exclusive over pair sums
  if (t < 196) {
    curL[2 * t]     = ex;
    curL[2 * t + 1] = ex + a0;
    S[p * 392 + 2 * t]     = e0 + ex;
    S[p * 392 + 2 * t + 1] = e0 + ex + a0;   // t=195 -> S[p][391] = e0+6250
  }
  __syncthreads();
  // pass 2: scatter packed records into MY private region (write-amp ~1)
  for (int e = t; e < CHUNK; e += 256) {
    int ss = ei[e0 + e];
    int dd = ei[NE + e0 + e];
    int b = (unsigned)dd >> 8;
    int pos = atomicAdd(&curL[b], 1);
    rec[e0 + pos] = ss | ((dd & 255) << 17);
  }
}

// ---- bucket totals from S boundaries: bsum[B] = sum_p (S[p][B+1]-S[p][B]) ----
__global__ __launch_bounds__(256) void bucketsum_kernel(const int* __restrict__ S,
    int* __restrict__ bsum) {
  __shared__ int sh[256];
  int B = blockIdx.x;
  int t = threadIdx.x;
  int c = 0;
  for (int p = t; p < NP; p += 256)
    c += S[p * 392 + B + 1] - S[p * 392 + B];
  sh[t] = c;
  __syncthreads();
  for (int o = 128; o > 0; o >>= 1) {
    if (t < o) sh[t] += sh[t + o];
    __syncthreads();
  }
  if (t == 0) bsum[B] = sh[0];
}

// ---- exclusive scan of 391 bucket totals ----
__global__ __launch_bounds__(512) void scan2_kernel(int* __restrict__ bsum) {
  __shared__ int sh[512];
  int t = threadIdx.x;
  int v = (t < NB) ? bsum[t] : 0;
  sh[t] = v;
  __syncthreads();
  for (int o = 1; o < 512; o <<= 1) {
    int x = (t >= o) ? sh[t - o] : 0;
    __syncthreads();
    sh[t] += x;
    __syncthreads();
  }
  if (t < NB) bsum[t] = sh[t] - v;   // exclusive
}

// ---- sorter: one block per bucket, 512 threads, 16-lane segment groups ----
__global__ __launch_bounds__(512) void sort_kernel(const int* __restrict__ rec,
    const int* __restrict__ S, const int* __restrict__ bsum,
    int* __restrict__ csroff, int* __restrict__ csrsrc) {
  __shared__ int cntL[256];
  __shared__ int curL[256];
  int t = threadIdx.x;
  int B = blockIdx.x;
  if (t < 256) cntL[t] = 0;
  __syncthreads();
  int lane = t & 15;          // 16-lane group: matches ~16-record avg segment
  int g = t >> 4;             // 32 groups per block
  // pass 1: per-node (dstLocal) histogram
  for (int p = g; p < NP; p += 32) {
    int s0 = S[p * 392 + B], s1 = S[p * 392 + B + 1];
    for (int e = s0 + lane; e < s1; e += 16)
      atomicAdd(&cntL[(unsigned)rec[e] >> 17], 1);
  }
  __syncthreads();
  // exclusive scan of 256 counters (threads >=256 just hit the barriers)
  int v = 0;
  if (t < 256) { v = cntL[t]; curL[t] = v; }
  __syncthreads();
  for (int o = 1; o < 256; o <<= 1) {
    int x = 0;
    if (t < 256 && t >= o) x = curL[t - o];
    __syncthreads();
    if (t < 256) curL[t] += x;
    __syncthreads();
  }
  int b0 = bsum[B];
  if (t < 256) {
    int excl = curL[t] - v;
    int node = B * 256 + t;
    if (node <= NN) csroff[node] = b0 + excl;  // bucket 390/t=160 -> csroff[NN]=NE
  }
  __syncthreads();
  if (t < 256) curL[t] = b0 + (curL[t] - v);
  __syncthreads();
  // pass 2: scatter records into block-owned csr range
  for (int p = g; p < NP; p += 32) {
    int s0 = S[p * 392 + B], s1 = S[p * 392 + B + 1];
    for (int e = s0 + lane; e < s1; e += 16) {
      int r = rec[e];
      int pos = atomicAdd(&curL[(unsigned)r >> 17], 1);
      csrsrc[pos] = r & 0x1FFFF;
    }
  }
}

// ---- aggregation: agg[i,:] = sum over in-edges of bf16 x[src,:] (wave/node) ----
__global__ __launch_bounds__(256) void agg_kernel(const int* __restrict__ off,
    const int* __restrict__ srcs, const bf16* __restrict__ xh,
    float* __restrict__ agg) {
  int t = threadIdx.x;
  int d = t & 63, q = t >> 6;
  int i = blockIdx.x * 4 + q;
  int e0 = off[i], e1 = off[i + 1];
  float s = 0.0f;
  int e = e0;
  for (; e + 8 <= e1; e += 8) {
    int j0 = srcs[e + 0], j1 = srcs[e + 1], j2 = srcs[e + 2], j3 = srcs[e + 3];
    int j4 = srcs[e + 4], j5 = srcs[e + 5], j6 = srcs[e + 6], j7 = srcs[e + 7];
    float v0 = __bfloat162float(xh[(long)j0 * D + d]);
    float v1 = __bfloat162float(xh[(long)j1 * D + d]);
    float v2 = __bfloat162float(xh[(long)j2 * D + d]);
    float v3 = __bfloat162float(xh[(long)j3 * D + d]);
    float v4 = __bfloat162float(xh[(long)j4 * D + d]);
    float v5 = __bfloat162float(xh[(long)j5 * D + d]);
    float v6 = __bfloat162float(xh[(long)j6 * D + d]);
    float v7 = __bfloat162float(xh[(long)j7 * D + d]);
    s += ((v0 + v1) + (v2 + v3)) + ((v4 + v5) + (v6 + v7));
  }
  for (; e < e1; e++) s += __bfloat162float(xh[(long)srcs[e] * D + d]);
  agg[(long)i * D + d] = s;
}

// ---- 64x64-tiled GEMM (K=64), 4x4 register tile per thread ----
__global__ __launch_bounds__(256) void gemm64_kernel(
    const float* __restrict__ X,
    const float* __restrict__ AGG, const float* __restrict__ epsv, int l,
    const float* __restrict__ W, const float* __restrict__ bias,
    float* Y, int leaky, int accum)
{
  __shared__ float Ws[64][64];     // Ws[k][d]
  __shared__ float XsT[64][64];    // XsT[k][row]
  int t = threadIdx.x;
  int i0 = blockIdx.x * 64;
  float alpha = (AGG != nullptr) ? (1.0f + epsv[l]) : 1.0f;

  {
    int wr = t >> 4;
    int wc = (t & 15) * 4;
    #pragma unroll
    for (int j = 0; j < 4; j++) {
      float4 w4 = *(const float4*)&W[(long)(wr + 16 * j) * D + wc];
      *(float4*)&Ws[wr + 16 * j][wc] = w4;
    }
  }
  {
    int row = t & 63;
    int gi = i0 + row;
    int gis = (gi < NN) ? gi : NN - 1;
    int kb = (t >> 6) * 16;
    #pragma unroll
    for (int j = 0; j < 4; j++) {
      int k = kb + 4 * j;
      float4 xv = *(const float4*)&X[(long)gis * D + k];
      if (AGG) {
        float4 a4 = *(const float4*)&AGG[(long)gis * D + k];
        xv.x = alpha * xv.x + a4.x;
        xv.y = alpha * xv.y + a4.y;
        xv.z = alpha * xv.z + a4.z;
        xv.w = alpha * xv.w + a4.w;
      }
      XsT[k + 0][row] = xv.x;
      XsT[k + 1][row] = xv.y;
      XsT[k + 2][row] = xv.z;
      XsT[k + 3][row] = xv.w;
    }
  }

  int c0 = (t & 15) * 4;
  int r0 = (t >> 4) * 4;
  float4 acc[4];
  if (accum) {
    #pragma unroll
    for (int r = 0; r < 4; r++) {
      int gi = i0 + r0 + r;
      int gis = (gi < NN) ? gi : NN - 1;
      acc[r] = *(const float4*)&Y[(long)gis * D + c0];
    }
  } else {
    float4 b4 = *(const float4*)&bias[c0];
    #pragma unroll
    for (int r = 0; r < 4; r++) acc[r] = b4;
  }
  __syncthreads();

  #pragma unroll 8
  for (int k = 0; k < 64; k++) {
    float4 w4 = *(const float4*)&Ws[k][c0];
    float4 x4 = *(const float4*)&XsT[k][r0];
    acc[0].x += x4.x * w4.x; acc[0].y += x4.x * w4.y;
    acc[0].z += x4.x * w4.z; acc[0].w += x4.x * w4.w;
    acc[1].x += x4.y * w4.x; acc[1].y += x4.y * w4.y;
    acc[1].z += x4.y * w4.z; acc[1].w += x4.y * w4.w;
    acc[2].x += x4.z * w4.x; acc[2].y += x4.z * w4.y;
    acc[2].z += x4.z * w4.z; acc[2].w += x4.z * w4.w;
    acc[3].x += x4.w * w4.x; acc[3].y += x4.w * w4.y;
    acc[3].z += x4.w * w4.z; acc[3].w += x4.w * w4.w;
  }

  #pragma unroll
  for (int r = 0; r < 4; r++) {
    int gi = i0 + r0 + r;
    if (gi < NN) {
      float4 v = acc[r];
      if (leaky) {
        v.x = (v.x >= 0.0f) ? v.x : 0.01f * v.x;
        v.y = (v.y >= 0.0f) ? v.y : 0.01f * v.y;
        v.z = (v.z >= 0.0f) ? v.z : 0.01f * v.z;
        v.w = (v.w >= 0.0f) ? v.w : 0.01f * v.w;
      }
      *(float4*)&Y[(long)gi * D + c0] = v;
    }
  }
}

// ---- BN stats ----
__global__ __launch_bounds__(256) void bn_stats_kernel(const float* __restrict__ Y,
    float* __restrict__ stats) {
  int tid = threadIdx.x;
  int d = tid & 63, q = tid >> 6;
  float s = 0.0f, ss = 0.0f;
  for (int i = blockIdx.x * 4 + q; i < NN; i += gridDim.x * 4) {
    float v = Y[(long)i * D + d];
    s += v;
    ss += v * v;
  }
  __shared__ float Ss[4][64], SSs[4][64];
  Ss[q][d] = s; SSs[q][d] = ss;
  __syncthreads();
  if (q == 0) {
    s  = Ss[0][d] + Ss[1][d] + Ss[2][d] + Ss[3][d];
    ss = SSs[0][d] + SSs[1][d] + SSs[2][d] + SSs[3][d];
    atomicAdd(&stats[d], s);
    atomicAdd(&stats[64 + d], ss);
  }
}

// ---- BN apply + leaky (+ optional bf16 mirror for the gather) ----
__global__ __launch_bounds__(256) void bn_apply_kernel(const float* __restrict__ Y,
    const float* __restrict__ stats,
    const float* __restrict__ g, const float* __restrict__ b,
    float* __restrict__ Out, bf16* __restrict__ Outh) {
  int idx = blockIdx.x * 256 + threadIdx.x;
  int i = idx >> 6, d = idx & 63;
  if (i >= NN) return;
  float invn = 1.0f / (float)NN;
  float mu = stats[d] * invn;
  float var = fmaxf(stats[64 + d] * invn - mu * mu, 0.0f);
  float sc = g[d] * rsqrtf(var + BN_EPS);
  float v = sc * (Y[(long)i * D + d] - mu) + b[d];
  v = (v >= 0.0f) ? v : 0.01f * v;
  Out[(long)i * D + d] = v;
  if (Outh) Outh[(long)i * D + d] = __float2bfloat16(v);
}

// ---- fc2 ----
__global__ __launch_bounds__(256) void fc2_kernel(const float* __restrict__ H,
    const float* __restrict__ W, const float* __restrict__ b,
    float* __restrict__ out) {
  int tid = threadIdx.x;
  int k = tid & 63, q = tid >> 6;
  int i = blockIdx.x * 4 + q;
  float v = (i < NN) ? H[(long)i * D + k] * W[k] : 0.0f;
  #pragma unroll
  for (int off = 32; off > 0; off >>= 1)
    v += __shfl_down(v, off);
  if (k == 0 && i < NN) {
    float x = v + b[0];
    out[i] = 1.0f / (1.0f + __expf(-x));
  }
}

extern "C" void kernel_launch(void* const* d_in, const int* in_sizes, int n_in,
                              void* d_out, int out_size, void* d_ws, size_t ws_size,
                              hipStream_t stream) {
  const int*   node_deg   = (const int*)d_in[0];
  const int*   edge_index = (const int*)d_in[1];
  const float* embed      = (const float*)d_in[2];
  const float* eps        = (const float*)d_in[3];
  const float* W1         = (const float*)d_in[4];
  const float* b1         = (const float*)d_in[5];
  const float* W2         = (const float*)d_in[6];
  const float* b2         = (const float*)d_in[7];
  const float* bn_g       = (const float*)d_in[8];
  const float* bn_b       = (const float*)d_in[9];
  const float* fc_W1      = (const float*)d_in[10];
  const float* fc_b1      = (const float*)d_in[11];
  const float* fc_bn_g    = (const float*)d_in[12];
  const float* fc_bn_b    = (const float*)d_in[13];
  const float* fc_W2      = (const float*)d_in[14];
  const float* fc_b2      = (const float*)d_in[15];

  // workspace: 4x[N,64] f32 (tmp aliased onto agg) + stats + sort arrays
  float* cur    = (float*)d_ws;                 // [N,64]
  float* nxt    = cur + (long)NN * D;           // [N,64]
  float* fc1acc = nxt + (long)NN * D;           // [N,64]
  float* agg    = fc1acc + (long)NN * D;        // [N,64]  (also "tmp")
  float* tmp    = agg;                          // alias: safe, row-local gemm
  float* stats  = agg + (long)NN * D;           // [128]
  int*   csroff = (int*)(stats + 128);          // [NN+1]
  int*   bsum   = csroff + NN + 1;              // [512]
  int*   csrsrc = bsum + 512;                   // [NE]
  int*   rec    = csrsrc + NE;                  // [NE] packed records
  int*   S      = rec + NE;                     // [NP*392]
  // bf16 gather mirror overlays rec: rec is dead after sort_kernel,
  // and embed_kernel (first xh write) launches after sort_kernel.
  bf16*  xh     = (bf16*)rec;                   // [N,64] bf16 (12.8 MB = NE*4 B)

  const int rowBlocks  = NN / 4;                 // 25000
  const int gemmBlocks = (NN + 63) / 64;         // 1563

  // ---- build CSR (by dst): private-region bucket sort, no global atomics ----
  bucket_kernel<<<NP, 256, 0, stream>>>(edge_index, rec, S);
  bucketsum_kernel<<<NB, 256, 0, stream>>>(S, bsum);
  scan2_kernel<<<1, 512, 0, stream>>>(bsum);
  sort_kernel<<<NB, 512, 0, stream>>>(rec, S, bsum, csroff, csrsrc);

  // ---- embedding + fc1 contribution of slice 0 ----
  embed_kernel<<<rowBlocks, 256, 0, stream>>>(node_deg, embed, cur, xh);
  gemm64_kernel<<<gemmBlocks, 256, 0, stream>>>(cur, nullptr, nullptr, 0,
      fc_W1, fc_b1, fc1acc, 0, 0);

  for (int l = 0; l < 3; ++l) {
    agg_kernel<<<rowBlocks, 256, 0, stream>>>(csroff, csrsrc, xh, agg);
    // tmp(=agg) = leaky(((1+eps)x + agg) @ W1 + b1)   [in-place, row-local]
    gemm64_kernel<<<gemmBlocks, 256, 0, stream>>>(cur, agg, eps, l,
        W1 + (long)l * D * D, b1 + (long)l * D, tmp, 1, 0);
    // nxt = tmp @ W2 + b2  (pre-BN)
    gemm64_kernel<<<gemmBlocks, 256, 0, stream>>>(tmp, nullptr, nullptr, 0,
        W2 + (long)l * D * D, b2 + (long)l * D, nxt, 0, 0);
    hipMemsetAsync(stats, 0, 128 * sizeof(float), stream);
    bn_stats_kernel<<<256, 256, 0, stream>>>(nxt, stats);
    bn_apply_kernel<<<rowBlocks, 256, 0, stream>>>(nxt, stats,
        bn_g + (long)l * D, bn_b + (long)l * D, nxt, xh);
    // fc1acc += nxt @ fc_W1[(l+1)*64 : (l+2)*64, :]
    gemm64_kernel<<<gemmBlocks, 256, 0, stream>>>(nxt, nullptr, nullptr, 0,
        fc_W1 + (long)(l + 1) * D * D, nullptr, fc1acc, 0, 1);
    float* t2 = cur; cur = nxt; nxt = t2;  // swap
  }

  // ---- fc1 BN + leaky -> tmp; fc2 + sigmoid -> out ----
  hipMemsetAsync(stats, 0, 128 * sizeof(float), stream);
  bn_stats_kernel<<<256, 256, 0, stream>>>(fc1acc, stats);
  bn_apply_kernel<<<rowBlocks, 256, 0, stream>>>(fc1acc, stats,
      fc_bn_g, fc_bn_b, tmp, nullptr);
  fc2_kernel<<<rowBlocks, 256, 0, stream>>>(tmp, fc_W2, fc_b2, (float*)d_out);
}